// Round 9
// baseline (498.835 us; speedup 1.0000x reference)
//
#include <hip/hip_runtime.h>
#include <hip/hip_bf16.h>
#include <cmath>

#define TPB 256

typedef __attribute__((ext_vector_type(8))) short s16x8;
typedef __attribute__((ext_vector_type(4))) float f32x4;
typedef unsigned short ushortT;

constexpr long long PSTR = 8454272;   // 514*514*32 ushorts per padded image
constexpr int HW = 512 * 512;

static __device__ __forceinline__ short f2bf(float f) {
    union { __hip_bfloat16 h; short s; } u;
    u.h = __float2bfloat16(f);
    return u.s;
}
static __device__ __forceinline__ float bf2f(unsigned short u) {
    union { unsigned int i; float f; } v;
    v.i = ((unsigned int)u) << 16;
    return v.f;
}
static __device__ __forceinline__ unsigned int pack2(float a, float b) {
    return (unsigned int)(unsigned short)f2bf(a) | ((unsigned int)(unsigned short)f2bf(b) << 16);
}

#define COMP(vec,k) ((k)==0?(vec).x:((k)==1?(vec).y:((k)==2?(vec).z:(vec).w)))

// ---------------------------------------------------------------------------
// Weight pack body. slot stride 10240 shorts; bias fp32 @ short-offset 9216.
// cdc fold: center tap -= theta * sum_taps
// ---------------------------------------------------------------------------
static __device__ void pack_body(const float* w, const float* bias, const float* theta,
                                 short* dst, int CO, int CI, int cog, int l)
{
    const int l15 = l & 15, sl = l >> 4;
    for (int t = 0; t < 9; ++t) {
        for (int mt = 0; mt < 2; ++mt) {
            const int co = cog * 32 + 16 * mt + l15;
            s16x8 p;
            #pragma unroll
            for (int i = 0; i < 8; ++i) {
                const int ci = 8 * sl + i;
                float val = 0.f;
                if (co < CO && ci < CI) {
                    val = w[((size_t)co * CI + ci) * 9 + t];
                    if (theta && t == 4) {
                        float s = 0.f;
                        for (int tt = 0; tt < 9; ++tt) s += w[((size_t)co * CI + ci) * 9 + tt];
                        val -= theta[0] * s;
                    }
                }
                p[i] = f2bf(val);
            }
            *(s16x8*)(dst + ((size_t)(t * 2 + mt) * 64 + l) * 8) = p;
        }
    }
    if (l < 32) {
        const int co = cog * 32 + l;
        ((float*)(dst + 9216))[l] = (bias && co < CO) ? bias[co] : 0.f;
    }
}

__global__ __launch_bounds__(64) void packall_k(
    const float* e1w, const float* e1b, const float* e2w, const float* e2b,
    const float* e3w, const float* e3b, const float* e4w, const float* e4b,
    const float* e5w, const float* e5b, const float* resw, const float* resb,
    const float* d1w, const float* d1b, const float* d2w, const float* d2b,
    const float* ctw, const float* ctb, const float* lfw, const float* lfb,
    short* wpack)
{
    const int s = blockIdx.x;
    const float *w, *b;
    int CO = 32, CI = 32, cog = 0;
    switch (s) {
        case 0: w = e1w; b = e1b; CI = 3; break;
        case 1: w = e2w; b = e2b; break;
        case 2: w = e3w; b = e3b; break;
        case 3: w = e4w; b = e4b; break;
        case 4: w = e5w; b = e5b; break;
        case 5: w = resw; b = resb; break;
        case 6: w = d1w; b = d1b; break;
        case 7: w = d2w; b = d2b; CO = 1; break;
        case 8: case 9: w = ctw; b = ctb; CO = 64; CI = 9; cog = s - 8; break;
        default: w = lfw; b = lfb; CO = 64; CI = 3; cog = s - 10; break;
    }
    pack_body(w, b, nullptr, wpack + (size_t)s * 10240, CO, CI, cog, threadIdx.x);
}

__global__ __launch_bounds__(64) void packcdc_k(
    const float* cdcw, const float* theta, short* wpack)
{
    const int b = blockIdx.x;
    pack_body(cdcw, nullptr, theta + b, wpack + (size_t)(12 + b) * 10240, 32, 32, 0, threadIdx.x);
}

// ---------------------------------------------------------------------------
// zero halo rings of 8 padded NHWC buffers (A2 z0..3, B2 z0..3)
// ---------------------------------------------------------------------------
__global__ __launch_bounds__(TPB) void zero_k(unsigned int* A2u, unsigned int* B2u)
{
    const int idx = blockIdx.x * TPB + threadIdx.x;
    if (idx >= 8 * 32832) return;
    const int q = idx / 32832, r = idx % 32832;
    unsigned int* P = (q < 4 ? A2u : B2u) + (size_t)(q & 3) * 4227136;
    const int RSU = 514 * 16;
    int off;
    if (r < 8224)       off = r;
    else if (r < 16448) off = 513 * RSU + (r - 8224);
    else if (r < 24640) { int u = r - 16448; off = (1 + (u >> 4)) * RSU + (u & 15); }
    else                { int u = r - 24640; off = (1 + (u >> 4)) * RSU + 513 * 16 + (u & 15); }
    P[off] = 0u;
}

// ---------------------------------------------------------------------------
// LDS-staged MFMA conv, fp32 NCHW input, EPI=4 only (ct/lf -> channel sums)
// ---------------------------------------------------------------------------
__global__ __launch_bounds__(TPB) void conv16m_k(
    const float* __restrict__ in0, const short* __restrict__ wpack0,
    float* __restrict__ part, int CI, int H, int W, int ntx, long long bstr_in)
{
    constexpr int RSX = 130;
    constexpr int ROWB = RSX * 64;
    __shared__ s16x8 lds_t[6 * RSX * 4];
    __shared__ float s_red[4][32];
    char* sb = (char*)lds_t;

    const int tid  = threadIdx.x;
    const int lane = tid & 63;
    const int wv   = tid >> 6;
    const float* in = in0 + (size_t)blockIdx.z * bstr_in;
    const int cog  = blockIdx.y;
    const short* wslot = wpack0 + (size_t)cog * 10240;
    const int tx = blockIdx.x % ntx, tyb = blockIdx.x / ntx;
    const int x0g = tx * 128, y0 = tyb * 4;
    const size_t HWl = (size_t)H * W;

    s16x8 wf[9][2];
    #pragma unroll
    for (int t = 0; t < 9; ++t)
        #pragma unroll
        for (int mt = 0; mt < 2; ++mt)
            wf[t][mt] = *(const s16x8*)(wslot + ((size_t)(t * 2 + mt) * 64 + lane) * 8);

    for (int q = tid; q < 768; q += TPB) {
        const int xq = q & 31, o = (q >> 5) & 3, row = q >> 7;
        const int gy = y0 - 1 + row;
        const bool yok = (gy >= 0) && (gy < H);
        const float* gp = in + (size_t)gy * W + x0g + 4 * xq;
        float4 v[8];
        #pragma unroll
        for (int j = 0; j < 8; ++j) {
            const int ci = 8 * o + j;
            if (yok && ci < CI) v[j] = *(const float4*)(gp + (size_t)ci * HWl);
            else                v[j] = make_float4(0.f, 0.f, 0.f, 0.f);
        }
        #pragma unroll
        for (int k = 0; k < 4; ++k) {
            const int lx = 1 + 4 * xq + k;
            const int vs = (lx + (lx >> 2)) & 3;
            s16x8 p;
            #pragma unroll
            for (int j = 0; j < 8; ++j) p[j] = f2bf(COMP(v[j], k));
            *(s16x8*)(sb + (row * RSX + lx) * 64 + ((o ^ vs) << 4)) = p;
        }
    }
    if (tid < 48) {
        const int side = tid & 1, o = (tid >> 1) & 3, row = tid >> 3;
        const int gy = y0 - 1 + row;
        const int lx = side ? 129 : 0;
        const int gx = x0g + (side ? 128 : -1);
        const bool ok = (gy >= 0) && (gy < H) && (gx >= 0) && (gx < W);
        s16x8 p;
        #pragma unroll
        for (int j = 0; j < 8; ++j) {
            const int ci = 8 * o + j;
            p[j] = f2bf((ok && ci < CI) ? in[(size_t)ci * HWl + (size_t)gy * W + gx] : 0.f);
        }
        const int vs = (lx + (lx >> 2)) & 3;
        *(s16x8*)(sb + (row * RSX + lx) * 64 + ((o ^ vs) << 4)) = p;
    }
    __syncthreads();

    const int xw = 32 * wv;
    const int l15 = lane & 15, slot = lane >> 4;
    int roff[3][2];
    #pragma unroll
    for (int dx = 0; dx < 3; ++dx)
        #pragma unroll
        for (int nt = 0; nt < 2; ++nt) {
            const int lx = xw + 16 * nt + dx + l15;
            const int vs = (lx + (lx >> 2)) & 3;
            roff[dx][nt] = lx * 64 + ((slot ^ vs) << 4);
        }

    const float* bptr = (const float*)(wslot + 9216);
    float ps[2][4];
    #pragma unroll
    for (int mt = 0; mt < 2; ++mt)
        #pragma unroll
        for (int reg = 0; reg < 4; ++reg) ps[mt][reg] = 0.f;

    for (int r2 = 0; r2 < 4; r2 += 2) {
        f32x4 acc[2][2][2];
        #pragma unroll
        for (int a = 0; a < 2; ++a)
            #pragma unroll
            for (int b = 0; b < 2; ++b)
                #pragma unroll
                for (int c = 0; c < 2; ++c)
                    #pragma unroll
                    for (int e = 0; e < 4; ++e) acc[a][b][c][e] = 0.f;

        #pragma unroll
        for (int dy = 0; dy < 3; ++dy) {
            const int rb0 = (r2 + dy) * ROWB;
            #pragma unroll
            for (int dx = 0; dx < 3; ++dx) {
                const int t = dy * 3 + dx;
                #pragma unroll
                for (int nt = 0; nt < 2; ++nt) {
                    const s16x8 b0 = *(const s16x8*)(sb + rb0 + roff[dx][nt]);
                    const s16x8 b1 = *(const s16x8*)(sb + rb0 + ROWB + roff[dx][nt]);
                    #pragma unroll
                    for (int mt = 0; mt < 2; ++mt) {
                        acc[0][mt][nt] = __builtin_amdgcn_mfma_f32_16x16x32_bf16(wf[t][mt], b0, acc[0][mt][nt], 0, 0, 0);
                        acc[1][mt][nt] = __builtin_amdgcn_mfma_f32_16x16x32_bf16(wf[t][mt], b1, acc[1][mt][nt], 0, 0, 0);
                    }
                }
            }
        }

        #pragma unroll
        for (int rr = 0; rr < 2; ++rr)
            #pragma unroll
            for (int mt = 0; mt < 2; ++mt)
                #pragma unroll
                for (int nt = 0; nt < 2; ++nt)
                    #pragma unroll
                    for (int reg = 0; reg < 4; ++reg)
                        ps[mt][reg] += fmaxf(acc[rr][mt][nt][reg] + bptr[16 * mt + 4 * slot + reg], 0.f);
    }

    #pragma unroll
    for (int mt = 0; mt < 2; ++mt)
        #pragma unroll
        for (int reg = 0; reg < 4; ++reg) {
            #pragma unroll
            for (int o = 1; o < 16; o <<= 1)
                ps[mt][reg] += __shfl_xor(ps[mt][reg], o, 64);
        }
    #pragma unroll
    for (int mt = 0; mt < 2; ++mt)
        #pragma unroll
        for (int reg = 0; reg < 4; ++reg)
            if (l15 == mt * 4 + reg)
                s_red[wv][16 * mt + 4 * slot + reg] = ps[mt][reg];
    __syncthreads();
    if (tid < 32) {
        const float s = s_red[0][tid] + s_red[1][tid] + s_red[2][tid] + s_red[3][tid];
        part[(((size_t)blockIdx.z * gridDim.y + blockIdx.y) * gridDim.x + blockIdx.x) * 32 + tid] = s;
    }
}

// ---------------------------------------------------------------------------
// enc1: narrow 64px x 4row conv, fp32 NCHW 3-ch input -> padded NHWC bf16.
// Only ci-octet 0 holds data; others zero-filled. LDS 25.3 KB.
// ---------------------------------------------------------------------------
__global__ __launch_bounds__(TPB) void enc1n_k(
    const float* __restrict__ x0p, const short* __restrict__ wslot,
    ushortT* __restrict__ outP0)
{
    constexpr int RSX = 66;
    constexpr int ROWB = RSX * 64;
    __shared__ s16x8 lds_t[6 * RSX * 4];
    char* sb = (char*)lds_t;

    const int z = blockIdx.z;
    const float* xin = x0p + (size_t)z * 3 * HW;

    const int tid = threadIdx.x, lane = tid & 63, wv = tid >> 6;
    const int bid = blockIdx.x;                     // 0..1023
    const int swz = (bid & 7) * 128 + (bid >> 3);
    const int x0 = (swz & 7) * 64, y0 = (swz >> 3) * 4;
    const int l15 = lane & 15, slot = lane >> 4;

    s16x8 wf[9][2];
    #pragma unroll
    for (int t = 0; t < 9; ++t)
        #pragma unroll
        for (int mt = 0; mt < 2; ++mt)
            wf[t][mt] = *(const s16x8*)(wslot + ((size_t)(t * 2 + mt) * 64 + lane) * 8);

    // stage: 1584 chunks; octet 0 gets 3 fp32 ch (bounds-checked), rest zero
    #pragma unroll
    for (int j = 0; j < 7; ++j) {
        const int p = j * 256 + tid;
        if (p < 1584) {
            const int row = p / 264;
            const int rem = p - row * 264;
            const int lx = rem >> 2, osl = rem & 3;
            const int o = osl ^ ((lx + (lx >> 2)) & 3);
            s16x8 pk;
            #pragma unroll
            for (int i = 0; i < 8; ++i) pk[i] = 0;
            if (o == 0) {
                const int gy = y0 + row - 1;
                const int gx = x0 + lx - 1;
                if (gy >= 0 && gy < 512 && gx >= 0 && gx < 512) {
                    #pragma unroll
                    for (int c = 0; c < 3; ++c)
                        pk[c] = f2bf(xin[((size_t)c * 512 + gy) * 512 + gx]);
                }
            }
            *(s16x8*)(sb + p * 16) = pk;
        }
    }
    __syncthreads();

    const int xw = 16 * wv;
    int roff[3];
    #pragma unroll
    for (int dx = 0; dx < 3; ++dx) {
        const int lx = xw + dx + l15;
        const int vs = (lx + (lx >> 2)) & 3;
        roff[dx] = lx * 64 + ((slot ^ vs) << 4);
    }
    const float* bptr = (const float*)(wslot + 9216);
    ushortT* outP = outP0 + (size_t)z * PSTR;

    #pragma unroll
    for (int r2 = 0; r2 < 4; r2 += 2) {
        f32x4 acc[2][2];
        #pragma unroll
        for (int a = 0; a < 2; ++a)
            #pragma unroll
            for (int b = 0; b < 2; ++b)
                #pragma unroll
                for (int e = 0; e < 4; ++e) acc[a][b][e] = 0.f;

        #pragma unroll
        for (int dy = 0; dy < 3; ++dy) {
            const int rb0 = (r2 + dy) * ROWB;
            #pragma unroll
            for (int dx = 0; dx < 3; ++dx) {
                const int tap = dy * 3 + dx;
                const s16x8 b0 = *(const s16x8*)(sb + rb0 + roff[dx]);
                const s16x8 b1 = *(const s16x8*)(sb + rb0 + ROWB + roff[dx]);
                #pragma unroll
                for (int mt = 0; mt < 2; ++mt) {
                    acc[0][mt] = __builtin_amdgcn_mfma_f32_16x16x32_bf16(wf[tap][mt], b0, acc[0][mt], 0, 0, 0);
                    acc[1][mt] = __builtin_amdgcn_mfma_f32_16x16x32_bf16(wf[tap][mt], b1, acc[1][mt], 0, 0, 0);
                }
            }
        }

        #pragma unroll
        for (int rr = 0; rr < 2; ++rr) {
            const int gy = y0 + r2 + rr;
            const int gx = x0 + xw + l15;
            #pragma unroll
            for (int mt = 0; mt < 2; ++mt) {
                const size_t off = ((size_t)(gy + 1) * 514 + gx + 1) * 32 + 16 * mt + 4 * slot;
                float v[4];
                #pragma unroll
                for (int reg = 0; reg < 4; ++reg)
                    v[reg] = fmaxf(acc[rr][mt][reg] + bptr[16 * mt + 4 * slot + reg], 0.f);
                *(uint2*)(outP + off) = make_uint2(pack2(v[0], v[1]), pack2(v[2], v[3]));
            }
        }
    }
}

// ---------------------------------------------------------------------------
// Pipelined 2-tile narrow conv on padded NHWC bf16. Block = 64px x 8 rows
// (two 4-row tiles). LDS = 10 rows x 66 x 32ch = 42.2 KB. Stage rows 0-5 ->
// bar -> issue rows 6-9 loads (held in 5xuint4) -> compute tile0 -> ds_write
// rows 6-9 -> bar -> compute tile1. EPI: 0 relu | 2 res (residual from LDS) |
// 3 d2+enhance.
// ---------------------------------------------------------------------------
template<int EPI>
__global__ __launch_bounds__(TPB) void dconv8_k(
    const ushortT* __restrict__ inP0, const short* __restrict__ wbase, int wstr,
    ushortT* __restrict__ outP0,
    const float* __restrict__ gamma0, const float* __restrict__ beta0,
    const float* __restrict__ xorig0, float* __restrict__ outE0, float* __restrict__ outM0)
{
    constexpr int MT = (EPI == 3) ? 1 : 2;
    constexpr int RSX = 66;
    constexpr int ROWB = RSX * 64;
    __shared__ s16x8 lds_t[10 * RSX * 4];   // 42,240 B
    char* sb = (char*)lds_t;

    const int z = blockIdx.z;
    const ushortT* inP = inP0 + (size_t)z * PSTR;
    const short* wslot = wbase + (size_t)z * wstr;

    const int tid = threadIdx.x, lane = tid & 63, wv = tid >> 6;
    const int bid = blockIdx.x;                    // 0..511
    const int swz = (bid & 7) * 64 + (bid >> 3);   // XCD-contiguous y-bands
    const int x0 = (swz & 7) * 64, y0 = (swz >> 3) * 8;
    const int l15 = lane & 15, slot = lane >> 4;

    s16x8 wf[9][MT];
    #pragma unroll
    for (int t = 0; t < 9; ++t)
        #pragma unroll
        for (int mt = 0; mt < MT; ++mt)
            wf[t][mt] = *(const s16x8*)(wslot + ((size_t)(t * 2 + mt) * 64 + lane) * 8);

    // --- stage padded rows y0..y0+5 (1584 chunks) ---
    #pragma unroll
    for (int j = 0; j < 7; ++j) {
        const int p = j * 256 + tid;
        if (p < 1584) {
            const int row = p / 264;
            const int rem = p - row * 264;
            const int lx = rem >> 2, osl = rem & 3;
            const int o = osl ^ ((lx + (lx >> 2)) & 3);
            *(uint4*)(sb + p * 16) =
                *(const uint4*)(inP + ((size_t)(y0 + row) * 514 + x0 + lx) * 32 + o * 8);
        }
    }
    __syncthreads();

    const int xw = 16 * wv;
    int roff[3];
    #pragma unroll
    for (int dx = 0; dx < 3; ++dx) {
        const int lx = xw + dx + l15;
        const int vs = (lx + (lx >> 2)) & 3;
        roff[dx] = lx * 64 + ((slot ^ vs) << 4);
    }
    const float* bptr = (const float*)(wslot + 9216);

    #pragma unroll
    for (int tile = 0; tile < 2; ++tile) {
        // issue next-tile stage loads (rows y0+6..y0+9), held in regs
        uint4 st[5];
        if (tile == 0) {
            #pragma unroll
            for (int j = 0; j < 5; ++j) {
                const int c = j * 256 + tid;
                if (c < 1056) {
                    const int row = 6 + c / 264;
                    const int rem = c % 264;
                    const int lx = rem >> 2, osl = rem & 3;
                    const int o = osl ^ ((lx + (lx >> 2)) & 3);
                    st[j] = *(const uint4*)(inP + ((size_t)(y0 + row) * 514 + x0 + lx) * 32 + o * 8);
                }
            }
        }

        // compute this tile (out rows y0+4*tile .. +3)
        #pragma unroll
        for (int r2 = 0; r2 < 4; r2 += 2) {
            f32x4 acc[2][MT];
            #pragma unroll
            for (int a = 0; a < 2; ++a)
                #pragma unroll
                for (int b = 0; b < MT; ++b)
                    #pragma unroll
                    for (int e = 0; e < 4; ++e) acc[a][b][e] = 0.f;

            #pragma unroll
            for (int dy = 0; dy < 3; ++dy) {
                const int rb0 = (4 * tile + r2 + dy) * ROWB;
                #pragma unroll
                for (int dx = 0; dx < 3; ++dx) {
                    const int tap = dy * 3 + dx;
                    const s16x8 b0 = *(const s16x8*)(sb + rb0 + roff[dx]);
                    const s16x8 b1 = *(const s16x8*)(sb + rb0 + ROWB + roff[dx]);
                    #pragma unroll
                    for (int mt = 0; mt < MT; ++mt) {
                        acc[0][mt] = __builtin_amdgcn_mfma_f32_16x16x32_bf16(wf[tap][mt], b0, acc[0][mt], 0, 0, 0);
                        acc[1][mt] = __builtin_amdgcn_mfma_f32_16x16x32_bf16(wf[tap][mt], b1, acc[1][mt], 0, 0, 0);
                    }
                }
            }

            #pragma unroll
            for (int rr = 0; rr < 2; ++rr) {
                const int gy = y0 + 4 * tile + r2 + rr;
                const int gx = x0 + xw + l15;
                if constexpr (EPI == 3) {
                    if (slot == 0) {
                        const float* xorig = xorig0 + (size_t)z * 3 * HW;
                        float* outE = outE0 + (size_t)z * 3 * HW;
                        float* outM = outM0 + (size_t)z * HW;
                        const float om = tanhf(acc[rr][0][0] + bptr[0]);
                        outM[(size_t)gy * 512 + gx] = om;
                        #pragma unroll
                        for (int c = 0; c < 3; ++c) {
                            const size_t xi = ((size_t)c * 512 + gy) * 512 + gx;
                            const float xv = xorig[xi];
                            outE[xi] = xv + om * (xv * xv - xv);
                        }
                    }
                } else {
                    ushortT* outP = outP0 + (size_t)z * PSTR;
                    #pragma unroll
                    for (int mt = 0; mt < MT; ++mt) {
                        const size_t off = ((size_t)(gy + 1) * 514 + gx + 1) * 32 + 16 * mt + 4 * slot;
                        float v[4];
                        #pragma unroll
                        for (int reg = 0; reg < 4; ++reg)
                            v[reg] = acc[rr][mt][reg] + bptr[16 * mt + 4 * slot + reg];
                        if constexpr (EPI == 0) {
                            #pragma unroll
                            for (int reg = 0; reg < 4; ++reg) v[reg] = fmaxf(v[reg], 0.f);
                        } else if constexpr (EPI == 2) {
                            // residual f_deco read from LDS (same px, this tile's rows)
                            const int prow = 4 * tile + r2 + rr + 1;
                            const int lxr = xw + l15 + 1;
                            const int vsr = (lxr + (lxr >> 2)) & 3;
                            const int oo = (2 * mt + (slot >> 1)) ^ vsr;
                            const uint2 din = *(const uint2*)(sb + (prow * RSX + lxr) * 64 + (oo << 4) + ((slot & 1) << 3));
                            const float* gamma = gamma0 + 32 * z;
                            const float* beta  = beta0 + 32 * z;
                            const int cb = 16 * mt + 4 * slot;
                            v[0] = bf2f((unsigned short)(din.x & 0xffff)) + gamma[cb + 0] * v[0] + beta[cb + 0];
                            v[1] = bf2f((unsigned short)(din.x >> 16))    + gamma[cb + 1] * v[1] + beta[cb + 1];
                            v[2] = bf2f((unsigned short)(din.y & 0xffff)) + gamma[cb + 2] * v[2] + beta[cb + 2];
                            v[3] = bf2f((unsigned short)(din.y >> 16))    + gamma[cb + 3] * v[3] + beta[cb + 3];
                        }
                        *(uint2*)(outP + off) = make_uint2(pack2(v[0], v[1]), pack2(v[2], v[3]));
                    }
                }
            }
        }

        // write held rows 6-9 into LDS (disjoint from tile0 reads), then bar
        if (tile == 0) {
            #pragma unroll
            for (int j = 0; j < 5; ++j) {
                const int c = j * 256 + tid;
                if (c < 1056) *(uint4*)(sb + (1584 + c) * 16) = st[j];
            }
            __syncthreads();
        }
    }
}

// ---------------------------------------------------------------------------
// Haar DWT (all 4 batches)
// ---------------------------------------------------------------------------
__global__ __launch_bounds__(TPB) void dwt_k(
    const float* __restrict__ x, float* __restrict__ haarA, float* __restrict__ hf)
{
    const int idx = blockIdx.x * TPB + threadIdx.x;
    if (idx >= 4 * 256 * 256) return;
    const int xo = idx & 255;
    const int yo = (idx >> 8) & 255;
    const int b  = idx >> 16;
    #pragma unroll
    for (int c = 0; c < 3; ++c) {
        const float* p = x + (((size_t)b * 3 + c) * 512 + 2 * yo) * 512 + 2 * xo;
        const float a = p[0], bb = p[1], cc = p[512], d = p[513];
        haarA[(((size_t)b * 3 + c) * 256 + yo) * 256 + xo] = 0.5f * (a + bb + cc + d);
        hf[(((size_t)b * 9 + 0 + c) * 256 + yo) * 256 + xo] = 0.5f * (a + bb - cc - d);
        hf[(((size_t)b * 9 + 3 + c) * 256 + yo) * 256 + xo] = 0.5f * (a - bb + cc - d);
        hf[(((size_t)b * 9 + 6 + c) * 256 + yo) * 256 + xo] = 0.5f * (a - bb - cc + d);
    }
}

// ---------------------------------------------------------------------------
// Finish channel means: br=0 -> amean (ct), br=1 -> am0 (lf).
// ---------------------------------------------------------------------------
__global__ __launch_bounds__(TPB) void meanfin_k(
    const float* __restrict__ part, float* __restrict__ amean, float* __restrict__ am0)
{
    const int br = blockIdx.x;
    const int o = threadIdx.x;
    const int z = o >> 6, co = o & 63, cog = co >> 5, c = co & 31;
    const float* p = part + (size_t)br * 32768 + ((size_t)(z * 2 + cog) * 128) * 32 + c;
    float s = 0.f;
    for (int j = 0; j < 128; ++j) s += p[j * 32];
    (br ? am0 : amean)[z * 64 + co] = s * (1.f / 65536.f);
}

// ---------------------------------------------------------------------------
// t1->t2->t3 chain, blockIdx.x = b
// ---------------------------------------------------------------------------
__global__ __launch_bounds__(64) void tchain_k(
    const float* __restrict__ amean,
    const float* __restrict__ t1w, const float* __restrict__ t1b,
    const float* __restrict__ t2w, const float* __restrict__ t2b,
    const float* __restrict__ t3w, const float* __restrict__ t3b,
    float* __restrict__ theta)
{
    const int b = blockIdx.x;
    const float* am = amean + b * 64;
    __shared__ float a0[64], a1[64], a2[64];
    const int co = threadIdx.x;
    a0[co] = am[co];
    __syncthreads();
    float s = t1b[co];
    #pragma unroll 8
    for (int ci = 0; ci < 64; ++ci) s = fmaf(t1w[co * 64 + ci], a0[ci], s);
    a1[co] = fmaxf(s, 0.f);
    __syncthreads();
    s = t2b[co];
    #pragma unroll 8
    for (int ci = 0; ci < 64; ++ci) s = fmaf(t2w[co * 64 + ci], a1[ci], s);
    a2[co] = fmaxf(s, 0.f);
    __syncthreads();
    if (co == 0) {
        float v = t3b[0];
        for (int ci = 0; ci < 64; ++ci) v = fmaf(t3w[ci], a2[ci], v);
        theta[b] = 1.f / (1.f + expf(-v));
    }
}

// ---------------------------------------------------------------------------
// wave-per-output FC. ACT 0 relu, 1 sigmoid, 2 tanh.
// ---------------------------------------------------------------------------
template<int ACT>
__global__ __launch_bounds__(TPB) void fcw_k(
    const float* __restrict__ in, const float* __restrict__ w,
    const float* __restrict__ bias, float* __restrict__ out, int K, int N)
{
    const int lane = threadIdx.x & 63, wv = threadIdx.x >> 6;
    const int idx = blockIdx.x * 4 + wv;
    if (idx >= 4 * N) return;
    const int b = idx / N, co = idx % N;
    float s = 0.f;
    for (int k = lane * 4; k < K; k += 256) {
        const float4 wv4 = *(const float4*)(w + (size_t)co * K + k);
        const float4 iv  = *(const float4*)(in + (size_t)b * K + k);
        s += wv4.x * iv.x + wv4.y * iv.y + wv4.z * iv.z + wv4.w * iv.w;
    }
    #pragma unroll
    for (int o = 32; o > 0; o >>= 1) s += __shfl_xor(s, o, 64);
    if (lane == 0) {
        s += bias[co];
        if (ACT == 0) s = fmaxf(s, 0.f);
        else if (ACT == 1) s = 1.f / (1.f + expf(-s));
        else s = tanhf(s);
        out[(size_t)b * N + co] = s;
    }
}

// ---------------------------------------------------------------------------
extern "C" void kernel_launch(void* const* d_in, const int* in_sizes, int n_in,
                              void* d_out, int out_size, void* d_ws, size_t ws_size,
                              hipStream_t stream)
{
    const float* x      = (const float*)d_in[0];
    const float* cdc_w  = (const float*)d_in[11];
    const float* t1_w   = (const float*)d_in[14];
    const float* t1_b   = (const float*)d_in[15];
    const float* t2_w   = (const float*)d_in[16];
    const float* t2_b   = (const float*)d_in[17];
    const float* t3_w   = (const float*)d_in[18];
    const float* t3_b   = (const float*)d_in[19];
    const float* fc1_w  = (const float*)d_in[22];
    const float* fc1_b  = (const float*)d_in[23];
    const float* fc2_w  = (const float*)d_in[24];
    const float* fc2_b  = (const float*)d_in[25];
    const float* fc3_w  = (const float*)d_in[26];
    const float* fc3_b  = (const float*)d_in[27];
    const float* g_w    = (const float*)d_in[28];
    const float* g_b    = (const float*)d_in[29];
    const float* be_w   = (const float*)d_in[30];
    const float* be_b   = (const float*)d_in[31];

    float* out = (float*)d_out;

    // workspace layout (haarA/hf alias B2; consumed before B2's first write)
    ushortT* A2 = (ushortT*)d_ws;                  // 4 x 16.9 MB
    ushortT* B2 = A2 + 4 * PSTR;                   // 4 x 16.9 MB
    float* haarA = (float*)B2;                     // (4,3,256,256) phase A only
    float* hf    = haarA + 786432;                 // (4,9,256,256) phase A only
    float* part  = (float*)(B2 + 4 * PSTR);        // 2 x 32768
    float* amean = part + 65536;                   // 256
    float* am0   = amean + 256;                    // 256
    float* am1   = am0 + 256;                      // 2048
    float* am2   = am1 + 2048;
    float* am3   = am2 + 2048;
    float* theta = am3 + 2048;                     // 4
    float* gamma = theta + 4;                      // 128 [4][32]
    float* beta  = gamma + 128;                    // 128
    short* wpack = (short*)(beta + 128);           // 16 x 10240 shorts
    const size_t need_bytes = (size_t)((char*)(wpack + 16 * 10240) - (char*)d_ws);
    if (ws_size < need_bytes) return;

    const dim3 blk(TPB);

    // --- phase A ---
    dwt_k<<<dim3((4 * 256 * 256 + TPB - 1) / TPB), blk, 0, stream>>>(x, haarA, hf);
    packall_k<<<dim3(12), dim3(64), 0, stream>>>(
        (const float*)d_in[1], (const float*)d_in[2], (const float*)d_in[3], (const float*)d_in[4],
        (const float*)d_in[5], (const float*)d_in[6], (const float*)d_in[7], (const float*)d_in[8],
        (const float*)d_in[9], (const float*)d_in[10], (const float*)d_in[32], (const float*)d_in[33],
        (const float*)d_in[34], (const float*)d_in[35], (const float*)d_in[36], (const float*)d_in[37],
        (const float*)d_in[12], (const float*)d_in[13], (const float*)d_in[20], (const float*)d_in[21],
        wpack);

    conv16m_k<<<dim3(128, 2, 4), blk, 0, stream>>>(hf, wpack + 8 * 10240, part,
        9, 256, 256, 2, (long long)9 * 65536);
    conv16m_k<<<dim3(128, 2, 4), blk, 0, stream>>>(haarA, wpack + 10 * 10240, part + 32768,
        3, 256, 256, 2, (long long)3 * 65536);

    // haarA/hf consumed -> zero halos of all 8 padded buffers
    zero_k<<<dim3((8 * 32832 + TPB - 1) / TPB), blk, 0, stream>>>((unsigned int*)A2, (unsigned int*)B2);

    meanfin_k<<<dim3(2), blk, 0, stream>>>(part, amean, am0);
    tchain_k<<<dim3(4), dim3(64), 0, stream>>>(amean, t1_w, t1_b, t2_w, t2_b, t3_w, t3_b, theta);
    fcw_k<0><<<dim3(512), blk, 0, stream>>>(am0, fc1_w, fc1_b, am1, 64, 512);
    fcw_k<0><<<dim3(512), blk, 0, stream>>>(am1, fc2_w, fc2_b, am2, 512, 512);
    fcw_k<1><<<dim3(512), blk, 0, stream>>>(am2, fc3_w, fc3_b, am3, 512, 512);
    fcw_k<1><<<dim3(32), blk, 0, stream>>>(am3, g_w, g_b, gamma, 512, 32);
    fcw_k<2><<<dim3(32), blk, 0, stream>>>(am3, be_w, be_b, beta, 512, 32);
    packcdc_k<<<dim3(4), dim3(64), 0, stream>>>(cdc_w, theta, wpack);

    // --- heavy chain: enc1n + 8 pipelined dconv8 dispatches ---
    const dim3 gE(1024, 1, 4);
    const dim3 gN(512, 1, 4);
    float* outM = out + (size_t)4 * 3 * HW;

    enc1n_k<<<gE, blk, 0, stream>>>(x, wpack, A2);
    dconv8_k<0><<<gN, blk, 0, stream>>>(A2, wpack + 1 * 10240, 0, B2, nullptr, nullptr, nullptr, nullptr, nullptr);
    dconv8_k<0><<<gN, blk, 0, stream>>>(B2, wpack + 2 * 10240, 0, A2, nullptr, nullptr, nullptr, nullptr, nullptr);
    dconv8_k<0><<<gN, blk, 0, stream>>>(A2, wpack + 3 * 10240, 0, B2, nullptr, nullptr, nullptr, nullptr, nullptr);
    dconv8_k<0><<<gN, blk, 0, stream>>>(B2, wpack + 4 * 10240, 0, A2, nullptr, nullptr, nullptr, nullptr, nullptr);
    // cdc (theta folded per batch): A2 -> B2 = f_deco
    dconv8_k<0><<<gN, blk, 0, stream>>>(A2, wpack + 12 * 10240, 10240, B2, nullptr, nullptr, nullptr, nullptr, nullptr);
    // res: B2 -> A2 (residual f_deco read from LDS)
    dconv8_k<2><<<gN, blk, 0, stream>>>(B2, wpack + 5 * 10240, 0, A2, gamma, beta, nullptr, nullptr, nullptr);
    // d1: A2 -> B2
    dconv8_k<0><<<gN, blk, 0, stream>>>(A2, wpack + 6 * 10240, 0, B2, nullptr, nullptr, nullptr, nullptr, nullptr);
    // d2 + tanh + enhance -> outputs
    dconv8_k<3><<<gN, blk, 0, stream>>>(B2, wpack + 7 * 10240, 0, nullptr, nullptr, nullptr, x, out, outM);
}

// Round 10
// 403.610 us; speedup vs baseline: 1.2359x; 1.2359x over previous
//
#include <hip/hip_runtime.h>
#include <hip/hip_bf16.h>
#include <cmath>

#define TPB 256

typedef __attribute__((ext_vector_type(8))) short s16x8;
typedef __attribute__((ext_vector_type(4))) float f32x4;
typedef unsigned short ushortT;

constexpr long long PSTR = 8454272;   // 514*514*32 ushorts per padded image
constexpr int HW = 512 * 512;

static __device__ __forceinline__ short f2bf(float f) {
    union { __hip_bfloat16 h; short s; } u;
    u.h = __float2bfloat16(f);
    return u.s;
}
static __device__ __forceinline__ float bf2f(unsigned short u) {
    union { unsigned int i; float f; } v;
    v.i = ((unsigned int)u) << 16;
    return v.f;
}
static __device__ __forceinline__ unsigned int pack2(float a, float b) {
    return (unsigned int)(unsigned short)f2bf(a) | ((unsigned int)(unsigned short)f2bf(b) << 16);
}

// global->LDS DMA, 16B per lane; lds dest = wave-uniform base + lane*16
#define GLOAD_LDS16(gp, lp) \
    __builtin_amdgcn_global_load_lds((const __attribute__((address_space(1))) void*)(gp), \
                                     (__attribute__((address_space(3))) void*)(lp), 16, 0, 0)

#define COMP(vec,k) ((k)==0?(vec).x:((k)==1?(vec).y:((k)==2?(vec).z:(vec).w)))

// ---------------------------------------------------------------------------
// Weight pack body. slot stride 10240 shorts; bias fp32 @ short-offset 9216.
// cdc fold: center tap -= theta * sum_taps
// ---------------------------------------------------------------------------
static __device__ void pack_body(const float* w, const float* bias, const float* theta,
                                 short* dst, int CO, int CI, int cog, int l)
{
    const int l15 = l & 15, sl = l >> 4;
    for (int t = 0; t < 9; ++t) {
        for (int mt = 0; mt < 2; ++mt) {
            const int co = cog * 32 + 16 * mt + l15;
            s16x8 p;
            #pragma unroll
            for (int i = 0; i < 8; ++i) {
                const int ci = 8 * sl + i;
                float val = 0.f;
                if (co < CO && ci < CI) {
                    val = w[((size_t)co * CI + ci) * 9 + t];
                    if (theta && t == 4) {
                        float s = 0.f;
                        for (int tt = 0; tt < 9; ++tt) s += w[((size_t)co * CI + ci) * 9 + tt];
                        val -= theta[0] * s;
                    }
                }
                p[i] = f2bf(val);
            }
            *(s16x8*)(dst + ((size_t)(t * 2 + mt) * 64 + l) * 8) = p;
        }
    }
    if (l < 32) {
        const int co = cog * 32 + l;
        ((float*)(dst + 9216))[l] = (bias && co < CO) ? bias[co] : 0.f;
    }
}

__global__ __launch_bounds__(64) void packall_k(
    const float* e1w, const float* e1b, const float* e2w, const float* e2b,
    const float* e3w, const float* e3b, const float* e4w, const float* e4b,
    const float* e5w, const float* e5b, const float* resw, const float* resb,
    const float* d1w, const float* d1b, const float* d2w, const float* d2b,
    const float* ctw, const float* ctb, const float* lfw, const float* lfb,
    short* wpack)
{
    const int s = blockIdx.x;
    const float *w, *b;
    int CO = 32, CI = 32, cog = 0;
    switch (s) {
        case 0: w = e1w; b = e1b; CI = 3; break;
        case 1: w = e2w; b = e2b; break;
        case 2: w = e3w; b = e3b; break;
        case 3: w = e4w; b = e4b; break;
        case 4: w = e5w; b = e5b; break;
        case 5: w = resw; b = resb; break;
        case 6: w = d1w; b = d1b; break;
        case 7: w = d2w; b = d2b; CO = 1; break;
        case 8: case 9: w = ctw; b = ctb; CO = 64; CI = 9; cog = s - 8; break;
        default: w = lfw; b = lfb; CO = 64; CI = 3; cog = s - 10; break;
    }
    pack_body(w, b, nullptr, wpack + (size_t)s * 10240, CO, CI, cog, threadIdx.x);
}

__global__ __launch_bounds__(64) void packcdc_k(
    const float* cdcw, const float* theta, short* wpack)
{
    const int b = blockIdx.x;
    pack_body(cdcw, nullptr, theta + b, wpack + (size_t)(12 + b) * 10240, 32, 32, 0, threadIdx.x);
}

// ---------------------------------------------------------------------------
// zero halo rings of 8 padded NHWC buffers (A2 z0..3, B2 z0..3)
// ---------------------------------------------------------------------------
__global__ __launch_bounds__(TPB) void zero_k(unsigned int* A2u, unsigned int* B2u)
{
    const int idx = blockIdx.x * TPB + threadIdx.x;
    if (idx >= 8 * 32832) return;
    const int q = idx / 32832, r = idx % 32832;
    unsigned int* P = (q < 4 ? A2u : B2u) + (size_t)(q & 3) * 4227136;
    const int RSU = 514 * 16;
    int off;
    if (r < 8224)       off = r;
    else if (r < 16448) off = 513 * RSU + (r - 8224);
    else if (r < 24640) { int u = r - 16448; off = (1 + (u >> 4)) * RSU + (u & 15); }
    else                { int u = r - 24640; off = (1 + (u >> 4)) * RSU + 513 * 16 + (u & 15); }
    P[off] = 0u;
}

// ---------------------------------------------------------------------------
// LDS-staged MFMA conv, fp32 NCHW input (ct/lf -> per-block channel sums)
// ---------------------------------------------------------------------------
__global__ __launch_bounds__(TPB) void conv16m_k(
    const float* __restrict__ in0, const short* __restrict__ wpack0,
    float* __restrict__ part, int CI, int H, int W, int ntx, long long bstr_in)
{
    constexpr int RSX = 130;
    constexpr int ROWB = RSX * 64;
    __shared__ s16x8 lds_t[6 * RSX * 4];
    __shared__ float s_red[4][32];
    char* sb = (char*)lds_t;

    const int tid  = threadIdx.x;
    const int lane = tid & 63;
    const int wv   = tid >> 6;
    const float* in = in0 + (size_t)blockIdx.z * bstr_in;
    const int cog  = blockIdx.y;
    const short* wslot = wpack0 + (size_t)cog * 10240;
    const int tx = blockIdx.x % ntx, tyb = blockIdx.x / ntx;
    const int x0g = tx * 128, y0 = tyb * 4;
    const size_t HWl = (size_t)H * W;

    s16x8 wf[9][2];
    #pragma unroll
    for (int t = 0; t < 9; ++t)
        #pragma unroll
        for (int mt = 0; mt < 2; ++mt)
            wf[t][mt] = *(const s16x8*)(wslot + ((size_t)(t * 2 + mt) * 64 + lane) * 8);

    for (int q = tid; q < 768; q += TPB) {
        const int xq = q & 31, o = (q >> 5) & 3, row = q >> 7;
        const int gy = y0 - 1 + row;
        const bool yok = (gy >= 0) && (gy < H);
        const float* gp = in + (size_t)gy * W + x0g + 4 * xq;
        float4 v[8];
        #pragma unroll
        for (int j = 0; j < 8; ++j) {
            const int ci = 8 * o + j;
            if (yok && ci < CI) v[j] = *(const float4*)(gp + (size_t)ci * HWl);
            else                v[j] = make_float4(0.f, 0.f, 0.f, 0.f);
        }
        #pragma unroll
        for (int k = 0; k < 4; ++k) {
            const int lx = 1 + 4 * xq + k;
            const int vs = (lx + (lx >> 2)) & 3;
            s16x8 p;
            #pragma unroll
            for (int j = 0; j < 8; ++j) p[j] = f2bf(COMP(v[j], k));
            *(s16x8*)(sb + (row * RSX + lx) * 64 + ((o ^ vs) << 4)) = p;
        }
    }
    if (tid < 48) {
        const int side = tid & 1, o = (tid >> 1) & 3, row = tid >> 3;
        const int gy = y0 - 1 + row;
        const int lx = side ? 129 : 0;
        const int gx = x0g + (side ? 128 : -1);
        const bool ok = (gy >= 0) && (gy < H) && (gx >= 0) && (gx < W);
        s16x8 p;
        #pragma unroll
        for (int j = 0; j < 8; ++j) {
            const int ci = 8 * o + j;
            p[j] = f2bf((ok && ci < CI) ? in[(size_t)ci * HWl + (size_t)gy * W + gx] : 0.f);
        }
        const int vs = (lx + (lx >> 2)) & 3;
        *(s16x8*)(sb + (row * RSX + lx) * 64 + ((o ^ vs) << 4)) = p;
    }
    __syncthreads();

    const int xw = 32 * wv;
    const int l15 = lane & 15, slot = lane >> 4;
    int roff[3][2];
    #pragma unroll
    for (int dx = 0; dx < 3; ++dx)
        #pragma unroll
        for (int nt = 0; nt < 2; ++nt) {
            const int lx = xw + 16 * nt + dx + l15;
            const int vs = (lx + (lx >> 2)) & 3;
            roff[dx][nt] = lx * 64 + ((slot ^ vs) << 4);
        }

    const float* bptr = (const float*)(wslot + 9216);
    float ps[2][4];
    #pragma unroll
    for (int mt = 0; mt < 2; ++mt)
        #pragma unroll
        for (int reg = 0; reg < 4; ++reg) ps[mt][reg] = 0.f;

    for (int r2 = 0; r2 < 4; r2 += 2) {
        f32x4 acc[2][2][2];
        #pragma unroll
        for (int a = 0; a < 2; ++a)
            #pragma unroll
            for (int b = 0; b < 2; ++b)
                #pragma unroll
                for (int c = 0; c < 2; ++c)
                    #pragma unroll
                    for (int e = 0; e < 4; ++e) acc[a][b][c][e] = 0.f;

        #pragma unroll
        for (int dy = 0; dy < 3; ++dy) {
            const int rb0 = (r2 + dy) * ROWB;
            #pragma unroll
            for (int dx = 0; dx < 3; ++dx) {
                const int t = dy * 3 + dx;
                #pragma unroll
                for (int nt = 0; nt < 2; ++nt) {
                    const s16x8 b0 = *(const s16x8*)(sb + rb0 + roff[dx][nt]);
                    const s16x8 b1 = *(const s16x8*)(sb + rb0 + ROWB + roff[dx][nt]);
                    #pragma unroll
                    for (int mt = 0; mt < 2; ++mt) {
                        acc[0][mt][nt] = __builtin_amdgcn_mfma_f32_16x16x32_bf16(wf[t][mt], b0, acc[0][mt][nt], 0, 0, 0);
                        acc[1][mt][nt] = __builtin_amdgcn_mfma_f32_16x16x32_bf16(wf[t][mt], b1, acc[1][mt][nt], 0, 0, 0);
                    }
                }
            }
        }

        #pragma unroll
        for (int rr = 0; rr < 2; ++rr)
            #pragma unroll
            for (int mt = 0; mt < 2; ++mt)
                #pragma unroll
                for (int nt = 0; nt < 2; ++nt)
                    #pragma unroll
                    for (int reg = 0; reg < 4; ++reg)
                        ps[mt][reg] += fmaxf(acc[rr][mt][nt][reg] + bptr[16 * mt + 4 * slot + reg], 0.f);
    }

    #pragma unroll
    for (int mt = 0; mt < 2; ++mt)
        #pragma unroll
        for (int reg = 0; reg < 4; ++reg) {
            #pragma unroll
            for (int o = 1; o < 16; o <<= 1)
                ps[mt][reg] += __shfl_xor(ps[mt][reg], o, 64);
        }
    #pragma unroll
    for (int mt = 0; mt < 2; ++mt)
        #pragma unroll
        for (int reg = 0; reg < 4; ++reg)
            if (l15 == mt * 4 + reg)
                s_red[wv][16 * mt + 4 * slot + reg] = ps[mt][reg];
    __syncthreads();
    if (tid < 32) {
        const float s = s_red[0][tid] + s_red[1][tid] + s_red[2][tid] + s_red[3][tid];
        part[(((size_t)blockIdx.z * gridDim.y + blockIdx.y) * gridDim.x + blockIdx.x) * 32 + tid] = s;
    }
}

// ---------------------------------------------------------------------------
// enc1: narrow 64px x 4row conv, fp32 NCHW 3-ch input -> padded NHWC bf16.
// ---------------------------------------------------------------------------
__global__ __launch_bounds__(TPB) void enc1n_k(
    const float* __restrict__ x0p, const short* __restrict__ wslot,
    ushortT* __restrict__ outP0)
{
    constexpr int RSX = 66;
    constexpr int ROWB = RSX * 64;
    __shared__ s16x8 lds_t[6 * RSX * 4];
    char* sb = (char*)lds_t;

    const int z = blockIdx.z;
    const float* xin = x0p + (size_t)z * 3 * HW;

    const int tid = threadIdx.x, lane = tid & 63, wv = tid >> 6;
    const int bid = blockIdx.x;
    const int swz = (bid & 7) * 128 + (bid >> 3);
    const int x0 = (swz & 7) * 64, y0 = (swz >> 3) * 4;
    const int l15 = lane & 15, slot = lane >> 4;

    s16x8 wf[9][2];
    #pragma unroll
    for (int t = 0; t < 9; ++t)
        #pragma unroll
        for (int mt = 0; mt < 2; ++mt)
            wf[t][mt] = *(const s16x8*)(wslot + ((size_t)(t * 2 + mt) * 64 + lane) * 8);

    #pragma unroll
    for (int j = 0; j < 7; ++j) {
        const int p = j * 256 + tid;
        if (p < 1584) {
            const int row = p / 264;
            const int rem = p - row * 264;
            const int lx = rem >> 2, osl = rem & 3;
            const int o = osl ^ ((lx + (lx >> 2)) & 3);
            s16x8 pk;
            #pragma unroll
            for (int i = 0; i < 8; ++i) pk[i] = 0;
            if (o == 0) {
                const int gy = y0 + row - 1;
                const int gx = x0 + lx - 1;
                if (gy >= 0 && gy < 512 && gx >= 0 && gx < 512) {
                    #pragma unroll
                    for (int c = 0; c < 3; ++c)
                        pk[c] = f2bf(xin[((size_t)c * 512 + gy) * 512 + gx]);
                }
            }
            *(s16x8*)(sb + p * 16) = pk;
        }
    }
    __syncthreads();

    const int xw = 16 * wv;
    int roff[3];
    #pragma unroll
    for (int dx = 0; dx < 3; ++dx) {
        const int lx = xw + dx + l15;
        const int vs = (lx + (lx >> 2)) & 3;
        roff[dx] = lx * 64 + ((slot ^ vs) << 4);
    }
    const float* bptr = (const float*)(wslot + 9216);
    ushortT* outP = outP0 + (size_t)z * PSTR;

    #pragma unroll
    for (int r2 = 0; r2 < 4; r2 += 2) {
        f32x4 acc[2][2];
        #pragma unroll
        for (int a = 0; a < 2; ++a)
            #pragma unroll
            for (int b = 0; b < 2; ++b)
                #pragma unroll
                for (int e = 0; e < 4; ++e) acc[a][b][e] = 0.f;

        #pragma unroll
        for (int dy = 0; dy < 3; ++dy) {
            const int rb0 = (r2 + dy) * ROWB;
            #pragma unroll
            for (int dx = 0; dx < 3; ++dx) {
                const int tap = dy * 3 + dx;
                const s16x8 b0 = *(const s16x8*)(sb + rb0 + roff[dx]);
                const s16x8 b1 = *(const s16x8*)(sb + rb0 + ROWB + roff[dx]);
                #pragma unroll
                for (int mt = 0; mt < 2; ++mt) {
                    acc[0][mt] = __builtin_amdgcn_mfma_f32_16x16x32_bf16(wf[tap][mt], b0, acc[0][mt], 0, 0, 0);
                    acc[1][mt] = __builtin_amdgcn_mfma_f32_16x16x32_bf16(wf[tap][mt], b1, acc[1][mt], 0, 0, 0);
                }
            }
        }

        #pragma unroll
        for (int rr = 0; rr < 2; ++rr) {
            const int gy = y0 + r2 + rr;
            const int gx = x0 + xw + l15;
            #pragma unroll
            for (int mt = 0; mt < 2; ++mt) {
                const size_t off = ((size_t)(gy + 1) * 514 + gx + 1) * 32 + 16 * mt + 4 * slot;
                float v[4];
                #pragma unroll
                for (int reg = 0; reg < 4; ++reg)
                    v[reg] = fmaxf(acc[rr][mt][reg] + bptr[16 * mt + 4 * slot + reg], 0.f);
                *(uint2*)(outP + off) = make_uint2(pack2(v[0], v[1]), pack2(v[2], v[3]));
            }
        }
    }
}

// ---------------------------------------------------------------------------
// Narrow-tile MFMA conv on padded NHWC bf16, staged via global_load_lds DMA.
// Tile: 64 px x 4 rows x 32 co. LDS = 6 x 66 x 32ch = 25.3 KB (6 blocks/CU).
// Stage: 1584 16B chunks, linear LDS dest (wave-uniform base + lane*16),
// octet swizzle folded into the per-lane GLOBAL source address.
// EPI: 0 relu | 2 res (residual from global) | 3 d2+enhance.
// ---------------------------------------------------------------------------
template<int EPI>
__global__ __launch_bounds__(TPB) void dconv64_k(
    const ushortT* __restrict__ inP0, const short* __restrict__ wbase, int wstr,
    ushortT* __restrict__ outP0,
    const float* __restrict__ gamma0, const float* __restrict__ beta0,
    const float* __restrict__ xorig0, float* __restrict__ outE0, float* __restrict__ outM0)
{
    constexpr int MT = (EPI == 3) ? 1 : 2;
    constexpr int RSX = 66;
    constexpr int ROWB = RSX * 64;
    __shared__ s16x8 lds_t[6 * RSX * 4];   // 25,344 B
    char* sb = (char*)lds_t;

    const int z = blockIdx.z;
    const ushortT* inP = inP0 + (size_t)z * PSTR;
    const short* wslot = wbase + (size_t)z * wstr;

    const int tid = threadIdx.x, lane = tid & 63, wv = tid >> 6;
    const int bid = blockIdx.x;                     // 0..1023
    const int swz = (bid & 7) * 128 + (bid >> 3);   // XCD-contiguous bands
    const int x0 = (swz & 7) * 64, y0 = (swz >> 3) * 4;
    const int l15 = lane & 15, slot = lane >> 4;

    s16x8 wf[9][MT];
    #pragma unroll
    for (int t = 0; t < 9; ++t)
        #pragma unroll
        for (int mt = 0; mt < MT; ++mt)
            wf[t][mt] = *(const s16x8*)(wslot + ((size_t)(t * 2 + mt) * 64 + lane) * 8);

    // --- stage via DMA: chunk p = (row*66+lx)*4+osl, LDS addr = p*16,
    // global octet o = osl ^ vs(lx) (pre-swizzled source, linear dest) ---
    #pragma unroll
    for (int j = 0; j < 6; ++j) {
        const int p = j * 256 + tid;
        const int row = p / 264;
        const int rem = p - row * 264;
        const int lx = rem >> 2, osl = rem & 3;
        const int o = osl ^ ((lx + (lx >> 2)) & 3);
        const ushortT* gp = inP + ((size_t)(y0 + row) * 514 + x0 + lx) * 32 + o * 8;
        GLOAD_LDS16(gp, sb + (size_t)(j * 256 + wv * 64) * 16);
    }
    if (tid < 48) {   // tail chunks 1536..1583 (wave 0, lanes 0-47; rest masked)
        const int p = 1536 + tid;
        const int row = p / 264;
        const int rem = p - row * 264;
        const int lx = rem >> 2, osl = rem & 3;
        const int o = osl ^ ((lx + (lx >> 2)) & 3);
        const ushortT* gp = inP + ((size_t)(y0 + row) * 514 + x0 + lx) * 32 + o * 8;
        GLOAD_LDS16(gp, sb + (size_t)1536 * 16);
    }
    __syncthreads();   // compiler drains vmcnt before s_barrier

    const int xw = 16 * wv;
    int roff[3];
    #pragma unroll
    for (int dx = 0; dx < 3; ++dx) {
        const int lx = xw + dx + l15;
        const int vs = (lx + (lx >> 2)) & 3;
        roff[dx] = lx * 64 + ((slot ^ vs) << 4);
    }
    const float* bptr = (const float*)(wslot + 9216);

    #pragma unroll
    for (int r2 = 0; r2 < 4; r2 += 2) {
        f32x4 acc[2][MT];
        #pragma unroll
        for (int a = 0; a < 2; ++a)
            #pragma unroll
            for (int b = 0; b < MT; ++b)
                #pragma unroll
                for (int e = 0; e < 4; ++e) acc[a][b][e] = 0.f;

        #pragma unroll
        for (int dy = 0; dy < 3; ++dy) {
            const int rb0 = (r2 + dy) * ROWB;
            #pragma unroll
            for (int dx = 0; dx < 3; ++dx) {
                const int tap = dy * 3 + dx;
                const s16x8 b0 = *(const s16x8*)(sb + rb0 + roff[dx]);
                const s16x8 b1 = *(const s16x8*)(sb + rb0 + ROWB + roff[dx]);
                #pragma unroll
                for (int mt = 0; mt < MT; ++mt) {
                    acc[0][mt] = __builtin_amdgcn_mfma_f32_16x16x32_bf16(wf[tap][mt], b0, acc[0][mt], 0, 0, 0);
                    acc[1][mt] = __builtin_amdgcn_mfma_f32_16x16x32_bf16(wf[tap][mt], b1, acc[1][mt], 0, 0, 0);
                }
            }
        }

        #pragma unroll
        for (int rr = 0; rr < 2; ++rr) {
            const int gy = y0 + r2 + rr;
            const int gx = x0 + xw + l15;
            if constexpr (EPI == 3) {
                if (slot == 0) {
                    const float* xorig = xorig0 + (size_t)z * 3 * HW;
                    float* outE = outE0 + (size_t)z * 3 * HW;
                    float* outM = outM0 + (size_t)z * HW;
                    const float om = tanhf(acc[rr][0][0] + bptr[0]);
                    outM[(size_t)gy * 512 + gx] = om;
                    #pragma unroll
                    for (int c = 0; c < 3; ++c) {
                        const size_t xi = ((size_t)c * 512 + gy) * 512 + gx;
                        const float xv = xorig[xi];
                        outE[xi] = xv + om * (xv * xv - xv);
                    }
                }
            } else {
                ushortT* outP = outP0 + (size_t)z * PSTR;
                #pragma unroll
                for (int mt = 0; mt < MT; ++mt) {
                    const size_t off = ((size_t)(gy + 1) * 514 + gx + 1) * 32 + 16 * mt + 4 * slot;
                    float v[4];
                    #pragma unroll
                    for (int reg = 0; reg < 4; ++reg)
                        v[reg] = acc[rr][mt][reg] + bptr[16 * mt + 4 * slot + reg];
                    if constexpr (EPI == 0) {
                        #pragma unroll
                        for (int reg = 0; reg < 4; ++reg) v[reg] = fmaxf(v[reg], 0.f);
                    } else if constexpr (EPI == 2) {
                        const float* gamma = gamma0 + 32 * z;
                        const float* beta  = beta0 + 32 * z;
                        const uint2 din = *(const uint2*)(inP + off);
                        const int cb = 16 * mt + 4 * slot;
                        v[0] = bf2f((unsigned short)(din.x & 0xffff)) + gamma[cb + 0] * v[0] + beta[cb + 0];
                        v[1] = bf2f((unsigned short)(din.x >> 16))    + gamma[cb + 1] * v[1] + beta[cb + 1];
                        v[2] = bf2f((unsigned short)(din.y & 0xffff)) + gamma[cb + 2] * v[2] + beta[cb + 2];
                        v[3] = bf2f((unsigned short)(din.y >> 16))    + gamma[cb + 3] * v[3] + beta[cb + 3];
                    }
                    *(uint2*)(outP + off) = make_uint2(pack2(v[0], v[1]), pack2(v[2], v[3]));
                }
            }
        }
    }
}

// ---------------------------------------------------------------------------
// Haar DWT (all 4 batches)
// ---------------------------------------------------------------------------
__global__ __launch_bounds__(TPB) void dwt_k(
    const float* __restrict__ x, float* __restrict__ haarA, float* __restrict__ hf)
{
    const int idx = blockIdx.x * TPB + threadIdx.x;
    if (idx >= 4 * 256 * 256) return;
    const int xo = idx & 255;
    const int yo = (idx >> 8) & 255;
    const int b  = idx >> 16;
    #pragma unroll
    for (int c = 0; c < 3; ++c) {
        const float* p = x + (((size_t)b * 3 + c) * 512 + 2 * yo) * 512 + 2 * xo;
        const float a = p[0], bb = p[1], cc = p[512], d = p[513];
        haarA[(((size_t)b * 3 + c) * 256 + yo) * 256 + xo] = 0.5f * (a + bb + cc + d);
        hf[(((size_t)b * 9 + 0 + c) * 256 + yo) * 256 + xo] = 0.5f * (a + bb - cc - d);
        hf[(((size_t)b * 9 + 3 + c) * 256 + yo) * 256 + xo] = 0.5f * (a - bb + cc - d);
        hf[(((size_t)b * 9 + 6 + c) * 256 + yo) * 256 + xo] = 0.5f * (a - bb - cc + d);
    }
}

// ---------------------------------------------------------------------------
// Finish channel means: br=0 -> amean (ct), br=1 -> am0 (lf).
// ---------------------------------------------------------------------------
__global__ __launch_bounds__(TPB) void meanfin_k(
    const float* __restrict__ part, float* __restrict__ amean, float* __restrict__ am0)
{
    const int br = blockIdx.x;
    const int o = threadIdx.x;
    const int z = o >> 6, co = o & 63, cog = co >> 5, c = co & 31;
    const float* p = part + (size_t)br * 32768 + ((size_t)(z * 2 + cog) * 128) * 32 + c;
    float s = 0.f;
    for (int j = 0; j < 128; ++j) s += p[j * 32];
    (br ? am0 : amean)[z * 64 + co] = s * (1.f / 65536.f);
}

// ---------------------------------------------------------------------------
// t1->t2->t3 chain, blockIdx.x = b
// ---------------------------------------------------------------------------
__global__ __launch_bounds__(64) void tchain_k(
    const float* __restrict__ amean,
    const float* __restrict__ t1w, const float* __restrict__ t1b,
    const float* __restrict__ t2w, const float* __restrict__ t2b,
    const float* __restrict__ t3w, const float* __restrict__ t3b,
    float* __restrict__ theta)
{
    const int b = blockIdx.x;
    const float* am = amean + b * 64;
    __shared__ float a0[64], a1[64], a2[64];
    const int co = threadIdx.x;
    a0[co] = am[co];
    __syncthreads();
    float s = t1b[co];
    #pragma unroll 8
    for (int ci = 0; ci < 64; ++ci) s = fmaf(t1w[co * 64 + ci], a0[ci], s);
    a1[co] = fmaxf(s, 0.f);
    __syncthreads();
    s = t2b[co];
    #pragma unroll 8
    for (int ci = 0; ci < 64; ++ci) s = fmaf(t2w[co * 64 + ci], a1[ci], s);
    a2[co] = fmaxf(s, 0.f);
    __syncthreads();
    if (co == 0) {
        float v = t3b[0];
        for (int ci = 0; ci < 64; ++ci) v = fmaf(t3w[ci], a2[ci], v);
        theta[b] = 1.f / (1.f + expf(-v));
    }
}

// ---------------------------------------------------------------------------
// wave-per-output FC. ACT 0 relu, 1 sigmoid, 2 tanh.
// ---------------------------------------------------------------------------
template<int ACT>
__global__ __launch_bounds__(TPB) void fcw_k(
    const float* __restrict__ in, const float* __restrict__ w,
    const float* __restrict__ bias, float* __restrict__ out, int K, int N)
{
    const int lane = threadIdx.x & 63, wv = threadIdx.x >> 6;
    const int idx = blockIdx.x * 4 + wv;
    if (idx >= 4 * N) return;
    const int b = idx / N, co = idx % N;
    float s = 0.f;
    for (int k = lane * 4; k < K; k += 256) {
        const float4 wv4 = *(const float4*)(w + (size_t)co * K + k);
        const float4 iv  = *(const float4*)(in + (size_t)b * K + k);
        s += wv4.x * iv.x + wv4.y * iv.y + wv4.z * iv.z + wv4.w * iv.w;
    }
    #pragma unroll
    for (int o = 32; o > 0; o >>= 1) s += __shfl_xor(s, o, 64);
    if (lane == 0) {
        s += bias[co];
        if (ACT == 0) s = fmaxf(s, 0.f);
        else if (ACT == 1) s = 1.f / (1.f + expf(-s));
        else s = tanhf(s);
        out[(size_t)b * N + co] = s;
    }
}

// ---------------------------------------------------------------------------
extern "C" void kernel_launch(void* const* d_in, const int* in_sizes, int n_in,
                              void* d_out, int out_size, void* d_ws, size_t ws_size,
                              hipStream_t stream)
{
    const float* x      = (const float*)d_in[0];
    const float* cdc_w  = (const float*)d_in[11];
    const float* t1_w   = (const float*)d_in[14];
    const float* t1_b   = (const float*)d_in[15];
    const float* t2_w   = (const float*)d_in[16];
    const float* t2_b   = (const float*)d_in[17];
    const float* t3_w   = (const float*)d_in[18];
    const float* t3_b   = (const float*)d_in[19];
    const float* fc1_w  = (const float*)d_in[22];
    const float* fc1_b  = (const float*)d_in[23];
    const float* fc2_w  = (const float*)d_in[24];
    const float* fc2_b  = (const float*)d_in[25];
    const float* fc3_w  = (const float*)d_in[26];
    const float* fc3_b  = (const float*)d_in[27];
    const float* g_w    = (const float*)d_in[28];
    const float* g_b    = (const float*)d_in[29];
    const float* be_w   = (const float*)d_in[30];
    const float* be_b   = (const float*)d_in[31];

    float* out = (float*)d_out;

    // workspace layout (haarA/hf alias B2; consumed before B2's first write)
    ushortT* A2 = (ushortT*)d_ws;                  // 4 x 16.9 MB
    ushortT* B2 = A2 + 4 * PSTR;                   // 4 x 16.9 MB
    float* haarA = (float*)B2;                     // (4,3,256,256) phase A only
    float* hf    = haarA + 786432;                 // (4,9,256,256) phase A only
    float* part  = (float*)(B2 + 4 * PSTR);        // 2 x 32768
    float* amean = part + 65536;                   // 256
    float* am0   = amean + 256;                    // 256
    float* am1   = am0 + 256;                      // 2048
    float* am2   = am1 + 2048;
    float* am3   = am2 + 2048;
    float* theta = am3 + 2048;                     // 4
    float* gamma = theta + 4;                      // 128 [4][32]
    float* beta  = gamma + 128;                    // 128
    short* wpack = (short*)(beta + 128);           // 16 x 10240 shorts
    const size_t need_bytes = (size_t)((char*)(wpack + 16 * 10240) - (char*)d_ws);
    if (ws_size < need_bytes) return;

    const dim3 blk(TPB);

    // --- phase A ---
    dwt_k<<<dim3((4 * 256 * 256 + TPB - 1) / TPB), blk, 0, stream>>>(x, haarA, hf);
    packall_k<<<dim3(12), dim3(64), 0, stream>>>(
        (const float*)d_in[1], (const float*)d_in[2], (const float*)d_in[3], (const float*)d_in[4],
        (const float*)d_in[5], (const float*)d_in[6], (const float*)d_in[7], (const float*)d_in[8],
        (const float*)d_in[9], (const float*)d_in[10], (const float*)d_in[32], (const float*)d_in[33],
        (const float*)d_in[34], (const float*)d_in[35], (const float*)d_in[36], (const float*)d_in[37],
        (const float*)d_in[12], (const float*)d_in[13], (const float*)d_in[20], (const float*)d_in[21],
        wpack);

    conv16m_k<<<dim3(128, 2, 4), blk, 0, stream>>>(hf, wpack + 8 * 10240, part,
        9, 256, 256, 2, (long long)9 * 65536);
    conv16m_k<<<dim3(128, 2, 4), blk, 0, stream>>>(haarA, wpack + 10 * 10240, part + 32768,
        3, 256, 256, 2, (long long)3 * 65536);

    // haarA/hf consumed -> zero halos of all 8 padded buffers
    zero_k<<<dim3((8 * 32832 + TPB - 1) / TPB), blk, 0, stream>>>((unsigned int*)A2, (unsigned int*)B2);

    meanfin_k<<<dim3(2), blk, 0, stream>>>(part, amean, am0);
    tchain_k<<<dim3(4), dim3(64), 0, stream>>>(amean, t1_w, t1_b, t2_w, t2_b, t3_w, t3_b, theta);
    fcw_k<0><<<dim3(512), blk, 0, stream>>>(am0, fc1_w, fc1_b, am1, 64, 512);
    fcw_k<0><<<dim3(512), blk, 0, stream>>>(am1, fc2_w, fc2_b, am2, 512, 512);
    fcw_k<1><<<dim3(512), blk, 0, stream>>>(am2, fc3_w, fc3_b, am3, 512, 512);
    fcw_k<1><<<dim3(32), blk, 0, stream>>>(am3, g_w, g_b, gamma, 512, 32);
    fcw_k<2><<<dim3(32), blk, 0, stream>>>(am3, be_w, be_b, beta, 512, 32);
    packcdc_k<<<dim3(4), dim3(64), 0, stream>>>(cdc_w, theta, wpack);

    // --- heavy chain: enc1n + 8 DMA-staged dconv64 dispatches ---
    const dim3 gN(1024, 1, 4);
    float* outM = out + (size_t)4 * 3 * HW;

    enc1n_k<<<gN, blk, 0, stream>>>(x, wpack, A2);
    dconv64_k<0><<<gN, blk, 0, stream>>>(A2, wpack + 1 * 10240, 0, B2, nullptr, nullptr, nullptr, nullptr, nullptr);
    dconv64_k<0><<<gN, blk, 0, stream>>>(B2, wpack + 2 * 10240, 0, A2, nullptr, nullptr, nullptr, nullptr, nullptr);
    dconv64_k<0><<<gN, blk, 0, stream>>>(A2, wpack + 3 * 10240, 0, B2, nullptr, nullptr, nullptr, nullptr, nullptr);
    dconv64_k<0><<<gN, blk, 0, stream>>>(B2, wpack + 4 * 10240, 0, A2, nullptr, nullptr, nullptr, nullptr, nullptr);
    // cdc (theta folded per batch): A2 -> B2 = f_deco
    dconv64_k<0><<<gN, blk, 0, stream>>>(A2, wpack + 12 * 10240, 10240, B2, nullptr, nullptr, nullptr, nullptr, nullptr);
    // res: B2 -> A2
    dconv64_k<2><<<gN, blk, 0, stream>>>(B2, wpack + 5 * 10240, 0, A2, gamma, beta, nullptr, nullptr, nullptr);
    // d1: A2 -> B2
    dconv64_k<0><<<gN, blk, 0, stream>>>(A2, wpack + 6 * 10240, 0, B2, nullptr, nullptr, nullptr, nullptr, nullptr);
    // d2 + tanh + enhance -> outputs
    dconv64_k<3><<<gN, blk, 0, stream>>>(B2, wpack + 7 * 10240, 0, nullptr, nullptr, nullptr, x, out, outM);
}

// Round 11
// 400.529 us; speedup vs baseline: 1.2454x; 1.0077x over previous
//
#include <hip/hip_runtime.h>
#include <hip/hip_bf16.h>
#include <cmath>

#define TPB 256

typedef __attribute__((ext_vector_type(8))) short s16x8;
typedef __attribute__((ext_vector_type(4))) float f32x4;
typedef unsigned short ushortT;

constexpr long long PSTR = 8454272;   // 514*514*32 ushorts per padded image
constexpr int HW = 512 * 512;

static __device__ __forceinline__ short f2bf(float f) {
    union { __hip_bfloat16 h; short s; } u;
    u.h = __float2bfloat16(f);
    return u.s;
}
static __device__ __forceinline__ float bf2f(unsigned short u) {
    union { unsigned int i; float f; } v;
    v.i = ((unsigned int)u) << 16;
    return v.f;
}
static __device__ __forceinline__ unsigned int pack2(float a, float b) {
    return (unsigned int)(unsigned short)f2bf(a) | ((unsigned int)(unsigned short)f2bf(b) << 16);
}

// global->LDS DMA, 16B per lane; lds dest = wave-uniform base + lane*16
#define GLOAD_LDS16(gp, lp) \
    __builtin_amdgcn_global_load_lds((const __attribute__((address_space(1))) void*)(gp), \
                                     (__attribute__((address_space(3))) void*)(lp), 16, 0, 0)

// ---------------------------------------------------------------------------
// Weight pack body. slot stride 10240 shorts; bias fp32 @ short-offset 9216.
// Packed ci position = ci_off + source ci (zeros elsewhere; K padded to 32).
// cdc fold: center tap -= theta * sum_taps
// ---------------------------------------------------------------------------
static __device__ void pack_body(const float* w, const float* bias, const float* theta,
                                 short* dst, int CO, int CI_src, int ci_off, int cog, int l)
{
    const int l15 = l & 15, sl = l >> 4;
    for (int t = 0; t < 9; ++t) {
        for (int mt = 0; mt < 2; ++mt) {
            const int co = cog * 32 + 16 * mt + l15;
            s16x8 p;
            #pragma unroll
            for (int i = 0; i < 8; ++i) {
                const int pci = 8 * sl + i;
                float val = 0.f;
                if (co < CO && pci >= ci_off && pci < ci_off + CI_src) {
                    const int ci = pci - ci_off;
                    val = w[((size_t)co * CI_src + ci) * 9 + t];
                    if (theta && t == 4) {
                        float s = 0.f;
                        for (int tt = 0; tt < 9; ++tt) s += w[((size_t)co * CI_src + ci) * 9 + tt];
                        val -= theta[0] * s;
                    }
                }
                p[i] = f2bf(val);
            }
            *(s16x8*)(dst + ((size_t)(t * 2 + mt) * 64 + l) * 8) = p;
        }
    }
    if (l < 32) {
        const int co = cog * 32 + l;
        ((float*)(dst + 9216))[l] = (bias && co < CO) ? bias[co] : 0.f;
    }
}

__global__ __launch_bounds__(64) void packall_k(
    const float* e1w, const float* e1b, const float* e2w, const float* e2b,
    const float* e3w, const float* e3b, const float* e4w, const float* e4b,
    const float* e5w, const float* e5b, const float* resw, const float* resb,
    const float* d1w, const float* d1b, const float* d2w, const float* d2b,
    const float* ctw, const float* ctb, const float* lfw, const float* lfb,
    short* wpack)
{
    const int s = blockIdx.x;
    const float *w, *b;
    int CO = 32, CI = 32, coff = 0, cog = 0;
    switch (s) {
        case 0: w = e1w; b = e1b; CI = 3; break;
        case 1: w = e2w; b = e2b; break;
        case 2: w = e3w; b = e3b; break;
        case 3: w = e4w; b = e4b; break;
        case 4: w = e5w; b = e5b; break;
        case 5: w = resw; b = resb; break;
        case 6: w = d1w; b = d1b; break;
        case 7: w = d2w; b = d2b; CO = 1; break;
        case 8: case 9: w = ctw; b = ctb; CO = 64; CI = 9; cog = s - 8; break;
        default: w = lfw; b = lfb; CO = 64; CI = 3; coff = 9; cog = s - 10; break;
    }
    pack_body(w, b, nullptr, wpack + (size_t)s * 10240, CO, CI, coff, cog, threadIdx.x);
}

__global__ __launch_bounds__(64) void packcdc_k(
    const float* cdcw, const float* theta, short* wpack)
{
    const int b = blockIdx.x;
    pack_body(cdcw, nullptr, theta + b, wpack + (size_t)(12 + b) * 10240, 32, 32, 0, 0, threadIdx.x);
}

// ---------------------------------------------------------------------------
// zero halo rings of 8 padded NHWC buffers (A2 z0..3, B2 z0..3)
// ---------------------------------------------------------------------------
__global__ __launch_bounds__(TPB) void zero_k(unsigned int* A2u, unsigned int* B2u)
{
    const int idx = blockIdx.x * TPB + threadIdx.x;
    if (idx >= 8 * 32832) return;
    const int q = idx / 32832, r = idx % 32832;
    unsigned int* P = (q < 4 ? A2u : B2u) + (size_t)(q & 3) * 4227136;
    const int RSU = 514 * 16;
    int off;
    if (r < 8224)       off = r;
    else if (r < 16448) off = 513 * RSU + (r - 8224);
    else if (r < 24640) { int u = r - 16448; off = (1 + (u >> 4)) * RSU + (u & 15); }
    else                { int u = r - 24640; off = (1 + (u >> 4)) * RSU + 513 * 16 + (u & 15); }
    P[off] = 0u;
}

// ---------------------------------------------------------------------------
// Fused ct+lf conv -> per-block channel partial sums. Narrow 64px x 4row
// tiles on 256x256, fp32 inputs staged to bf16 LDS. Packed ci: 0-8 = hf,
// 9-11 = haarA, 12-31 zero. blockIdx.y = cog: 0,1 = ct co 0-63 (slot 8,9),
// 2,3 = lf co 0-63 (slot 10,11). part[((z*4+cog)*256 + bid)*32 + c].
// ---------------------------------------------------------------------------
__global__ __launch_bounds__(TPB) void ctlf_k(
    const float* __restrict__ hf0, const float* __restrict__ haarA0,
    const short* __restrict__ wpack8, float* __restrict__ part)
{
    constexpr int RSX = 66;
    constexpr int ROWB = RSX * 64;
    __shared__ s16x8 lds_t[6 * RSX * 4];
    __shared__ float s_red[4][32];
    char* sb = (char*)lds_t;

    const int z = blockIdx.z, cog = blockIdx.y;
    const int bid = blockIdx.x;                 // 0..255
    const int x0 = (bid & 3) * 64, y0 = (bid >> 2) * 4;
    const int tid = threadIdx.x, lane = tid & 63, wv = tid >> 6;
    const int l15 = lane & 15, slot = lane >> 4;

    const short* wslot = wpack8 + (size_t)cog * 10240;
    const float* hfz = hf0 + (size_t)z * 9 * 65536;
    const float* haz = haarA0 + (size_t)z * 3 * 65536;

    s16x8 wf[9][2];
    #pragma unroll
    for (int t = 0; t < 9; ++t)
        #pragma unroll
        for (int mt = 0; mt < 2; ++mt)
            wf[t][mt] = *(const s16x8*)(wslot + ((size_t)(t * 2 + mt) * 64 + lane) * 8);

    // stage: 1584 16B chunks; o=0 -> hf ch0-7, o=1 -> hf ch8 + haarA ch0-2
    #pragma unroll
    for (int j = 0; j < 7; ++j) {
        const int p = j * 256 + tid;
        if (p < 1584) {
            const int row = p / 264;
            const int rem = p - row * 264;
            const int lx = rem >> 2, osl = rem & 3;
            const int o = osl ^ ((lx + (lx >> 2)) & 3);
            s16x8 pk;
            #pragma unroll
            for (int i = 0; i < 8; ++i) pk[i] = 0;
            const int sy = y0 + row - 1, sx = x0 + lx - 1;
            if (o < 2 && sy >= 0 && sy < 256 && sx >= 0 && sx < 256) {
                const size_t base = (size_t)sy * 256 + sx;
                if (o == 0) {
                    #pragma unroll
                    for (int i = 0; i < 8; ++i)
                        pk[i] = f2bf(hfz[(size_t)i * 65536 + base]);
                } else {
                    pk[0] = f2bf(hfz[(size_t)8 * 65536 + base]);
                    pk[1] = f2bf(haz[base]);
                    pk[2] = f2bf(haz[(size_t)65536 + base]);
                    pk[3] = f2bf(haz[(size_t)2 * 65536 + base]);
                }
            }
            *(s16x8*)(sb + p * 16) = pk;
        }
    }
    __syncthreads();

    const int xw = 16 * wv;
    int roff[3];
    #pragma unroll
    for (int dx = 0; dx < 3; ++dx) {
        const int lx = xw + dx + l15;
        const int vs = (lx + (lx >> 2)) & 3;
        roff[dx] = lx * 64 + ((slot ^ vs) << 4);
    }
    const float* bptr = (const float*)(wslot + 9216);

    float ps[2][4];
    #pragma unroll
    for (int mt = 0; mt < 2; ++mt)
        #pragma unroll
        for (int reg = 0; reg < 4; ++reg) ps[mt][reg] = 0.f;

    #pragma unroll
    for (int r2 = 0; r2 < 4; r2 += 2) {
        f32x4 acc[2][2];
        #pragma unroll
        for (int a = 0; a < 2; ++a)
            #pragma unroll
            for (int b = 0; b < 2; ++b)
                #pragma unroll
                for (int e = 0; e < 4; ++e) acc[a][b][e] = 0.f;

        #pragma unroll
        for (int dy = 0; dy < 3; ++dy) {
            const int rb0 = (r2 + dy) * ROWB;
            #pragma unroll
            for (int dx = 0; dx < 3; ++dx) {
                const int tap = dy * 3 + dx;
                const s16x8 b0 = *(const s16x8*)(sb + rb0 + roff[dx]);
                const s16x8 b1 = *(const s16x8*)(sb + rb0 + ROWB + roff[dx]);
                #pragma unroll
                for (int mt = 0; mt < 2; ++mt) {
                    acc[0][mt] = __builtin_amdgcn_mfma_f32_16x16x32_bf16(wf[tap][mt], b0, acc[0][mt], 0, 0, 0);
                    acc[1][mt] = __builtin_amdgcn_mfma_f32_16x16x32_bf16(wf[tap][mt], b1, acc[1][mt], 0, 0, 0);
                }
            }
        }

        #pragma unroll
        for (int rr = 0; rr < 2; ++rr)
            #pragma unroll
            for (int mt = 0; mt < 2; ++mt)
                #pragma unroll
                for (int reg = 0; reg < 4; ++reg)
                    ps[mt][reg] += fmaxf(acc[rr][mt][reg] + bptr[16 * mt + 4 * slot + reg], 0.f);
    }

    // cross-lane reduce: 16-lane butterfly, scatter, cross-wave sum
    #pragma unroll
    for (int mt = 0; mt < 2; ++mt)
        #pragma unroll
        for (int reg = 0; reg < 4; ++reg) {
            #pragma unroll
            for (int o = 1; o < 16; o <<= 1)
                ps[mt][reg] += __shfl_xor(ps[mt][reg], o, 64);
        }
    #pragma unroll
    for (int mt = 0; mt < 2; ++mt)
        #pragma unroll
        for (int reg = 0; reg < 4; ++reg)
            if (l15 == mt * 4 + reg)
                s_red[wv][16 * mt + 4 * slot + reg] = ps[mt][reg];
    __syncthreads();
    if (tid < 32) {
        const float s = s_red[0][tid] + s_red[1][tid] + s_red[2][tid] + s_red[3][tid];
        part[(((size_t)z * 4 + cog) * 256 + bid) * 32 + tid] = s;
    }
}

// ---------------------------------------------------------------------------
// enc1: narrow 64px x 4row conv, fp32 NCHW 3-ch input -> padded NHWC bf16.
// ---------------------------------------------------------------------------
__global__ __launch_bounds__(TPB) void enc1n_k(
    const float* __restrict__ x0p, const short* __restrict__ wslot,
    ushortT* __restrict__ outP0)
{
    constexpr int RSX = 66;
    constexpr int ROWB = RSX * 64;
    __shared__ s16x8 lds_t[6 * RSX * 4];
    char* sb = (char*)lds_t;

    const int z = blockIdx.z;
    const float* xin = x0p + (size_t)z * 3 * HW;

    const int tid = threadIdx.x, lane = tid & 63, wv = tid >> 6;
    const int bid = blockIdx.x;
    const int swz = (bid & 7) * 128 + (bid >> 3);
    const int x0 = (swz & 7) * 64, y0 = (swz >> 3) * 4;
    const int l15 = lane & 15, slot = lane >> 4;

    s16x8 wf[9][2];
    #pragma unroll
    for (int t = 0; t < 9; ++t)
        #pragma unroll
        for (int mt = 0; mt < 2; ++mt)
            wf[t][mt] = *(const s16x8*)(wslot + ((size_t)(t * 2 + mt) * 64 + lane) * 8);

    #pragma unroll
    for (int j = 0; j < 7; ++j) {
        const int p = j * 256 + tid;
        if (p < 1584) {
            const int row = p / 264;
            const int rem = p - row * 264;
            const int lx = rem >> 2, osl = rem & 3;
            const int o = osl ^ ((lx + (lx >> 2)) & 3);
            s16x8 pk;
            #pragma unroll
            for (int i = 0; i < 8; ++i) pk[i] = 0;
            if (o == 0) {
                const int gy = y0 + row - 1;
                const int gx = x0 + lx - 1;
                if (gy >= 0 && gy < 512 && gx >= 0 && gx < 512) {
                    #pragma unroll
                    for (int c = 0; c < 3; ++c)
                        pk[c] = f2bf(xin[((size_t)c * 512 + gy) * 512 + gx]);
                }
            }
            *(s16x8*)(sb + p * 16) = pk;
        }
    }
    __syncthreads();

    const int xw = 16 * wv;
    int roff[3];
    #pragma unroll
    for (int dx = 0; dx < 3; ++dx) {
        const int lx = xw + dx + l15;
        const int vs = (lx + (lx >> 2)) & 3;
        roff[dx] = lx * 64 + ((slot ^ vs) << 4);
    }
    const float* bptr = (const float*)(wslot + 9216);
    ushortT* outP = outP0 + (size_t)z * PSTR;

    #pragma unroll
    for (int r2 = 0; r2 < 4; r2 += 2) {
        f32x4 acc[2][2];
        #pragma unroll
        for (int a = 0; a < 2; ++a)
            #pragma unroll
            for (int b = 0; b < 2; ++b)
                #pragma unroll
                for (int e = 0; e < 4; ++e) acc[a][b][e] = 0.f;

        #pragma unroll
        for (int dy = 0; dy < 3; ++dy) {
            const int rb0 = (r2 + dy) * ROWB;
            #pragma unroll
            for (int dx = 0; dx < 3; ++dx) {
                const int tap = dy * 3 + dx;
                const s16x8 b0 = *(const s16x8*)(sb + rb0 + roff[dx]);
                const s16x8 b1 = *(const s16x8*)(sb + rb0 + ROWB + roff[dx]);
                #pragma unroll
                for (int mt = 0; mt < 2; ++mt) {
                    acc[0][mt] = __builtin_amdgcn_mfma_f32_16x16x32_bf16(wf[tap][mt], b0, acc[0][mt], 0, 0, 0);
                    acc[1][mt] = __builtin_amdgcn_mfma_f32_16x16x32_bf16(wf[tap][mt], b1, acc[1][mt], 0, 0, 0);
                }
            }
        }

        #pragma unroll
        for (int rr = 0; rr < 2; ++rr) {
            const int gy = y0 + r2 + rr;
            const int gx = x0 + xw + l15;
            #pragma unroll
            for (int mt = 0; mt < 2; ++mt) {
                const size_t off = ((size_t)(gy + 1) * 514 + gx + 1) * 32 + 16 * mt + 4 * slot;
                float v[4];
                #pragma unroll
                for (int reg = 0; reg < 4; ++reg)
                    v[reg] = fmaxf(acc[rr][mt][reg] + bptr[16 * mt + 4 * slot + reg], 0.f);
                *(uint2*)(outP + off) = make_uint2(pack2(v[0], v[1]), pack2(v[2], v[3]));
            }
        }
    }
}

// ---------------------------------------------------------------------------
// Narrow-tile MFMA conv on padded NHWC bf16, staged via global_load_lds DMA.
// Tile: 64 px x 4 rows x 32 co. LDS = 6 x 66 x 32ch = 25.3 KB.
// EPI: 0 relu | 2 res (residual read from LDS) | 3 d2+enhance.
// ---------------------------------------------------------------------------
template<int EPI>
__global__ __launch_bounds__(TPB) void dconv64_k(
    const ushortT* __restrict__ inP0, const short* __restrict__ wbase, int wstr,
    ushortT* __restrict__ outP0,
    const float* __restrict__ gamma0, const float* __restrict__ beta0,
    const float* __restrict__ xorig0, float* __restrict__ outE0, float* __restrict__ outM0)
{
    constexpr int MT = (EPI == 3) ? 1 : 2;
    constexpr int RSX = 66;
    constexpr int ROWB = RSX * 64;
    __shared__ s16x8 lds_t[6 * RSX * 4];   // 25,344 B
    char* sb = (char*)lds_t;

    const int z = blockIdx.z;
    const ushortT* inP = inP0 + (size_t)z * PSTR;
    const short* wslot = wbase + (size_t)z * wstr;

    const int tid = threadIdx.x, lane = tid & 63, wv = tid >> 6;
    const int bid = blockIdx.x;                     // 0..1023
    const int swz = (bid & 7) * 128 + (bid >> 3);   // XCD-contiguous bands
    const int x0 = (swz & 7) * 64, y0 = (swz >> 3) * 4;
    const int l15 = lane & 15, slot = lane >> 4;

    s16x8 wf[9][MT];
    #pragma unroll
    for (int t = 0; t < 9; ++t)
        #pragma unroll
        for (int mt = 0; mt < MT; ++mt)
            wf[t][mt] = *(const s16x8*)(wslot + ((size_t)(t * 2 + mt) * 64 + lane) * 8);

    // --- stage via DMA: chunk p = (row*66+lx)*4+osl, LDS addr = p*16,
    // global octet o = osl ^ vs(lx) (pre-swizzled source, linear dest) ---
    #pragma unroll
    for (int j = 0; j < 6; ++j) {
        const int p = j * 256 + tid;
        const int row = p / 264;
        const int rem = p - row * 264;
        const int lx = rem >> 2, osl = rem & 3;
        const int o = osl ^ ((lx + (lx >> 2)) & 3);
        const ushortT* gp = inP + ((size_t)(y0 + row) * 514 + x0 + lx) * 32 + o * 8;
        GLOAD_LDS16(gp, sb + (size_t)(j * 256 + wv * 64) * 16);
    }
    if (tid < 48) {   // tail chunks 1536..1583
        const int p = 1536 + tid;
        const int row = p / 264;
        const int rem = p - row * 264;
        const int lx = rem >> 2, osl = rem & 3;
        const int o = osl ^ ((lx + (lx >> 2)) & 3);
        const ushortT* gp = inP + ((size_t)(y0 + row) * 514 + x0 + lx) * 32 + o * 8;
        GLOAD_LDS16(gp, sb + (size_t)1536 * 16);
    }
    __syncthreads();

    const int xw = 16 * wv;
    int roff[3];
    #pragma unroll
    for (int dx = 0; dx < 3; ++dx) {
        const int lx = xw + dx + l15;
        const int vs = (lx + (lx >> 2)) & 3;
        roff[dx] = lx * 64 + ((slot ^ vs) << 4);
    }
    const float* bptr = (const float*)(wslot + 9216);

    #pragma unroll
    for (int r2 = 0; r2 < 4; r2 += 2) {
        f32x4 acc[2][MT];
        #pragma unroll
        for (int a = 0; a < 2; ++a)
            #pragma unroll
            for (int b = 0; b < MT; ++b)
                #pragma unroll
                for (int e = 0; e < 4; ++e) acc[a][b][e] = 0.f;

        #pragma unroll
        for (int dy = 0; dy < 3; ++dy) {
            const int rb0 = (r2 + dy) * ROWB;
            #pragma unroll
            for (int dx = 0; dx < 3; ++dx) {
                const int tap = dy * 3 + dx;
                const s16x8 b0 = *(const s16x8*)(sb + rb0 + roff[dx]);
                const s16x8 b1 = *(const s16x8*)(sb + rb0 + ROWB + roff[dx]);
                #pragma unroll
                for (int mt = 0; mt < MT; ++mt) {
                    acc[0][mt] = __builtin_amdgcn_mfma_f32_16x16x32_bf16(wf[tap][mt], b0, acc[0][mt], 0, 0, 0);
                    acc[1][mt] = __builtin_amdgcn_mfma_f32_16x16x32_bf16(wf[tap][mt], b1, acc[1][mt], 0, 0, 0);
                }
            }
        }

        #pragma unroll
        for (int rr = 0; rr < 2; ++rr) {
            const int gy = y0 + r2 + rr;
            const int gx = x0 + xw + l15;
            if constexpr (EPI == 3) {
                if (slot == 0) {
                    const float* xorig = xorig0 + (size_t)z * 3 * HW;
                    float* outE = outE0 + (size_t)z * 3 * HW;
                    float* outM = outM0 + (size_t)z * HW;
                    const float om = tanhf(acc[rr][0][0] + bptr[0]);
                    outM[(size_t)gy * 512 + gx] = om;
                    #pragma unroll
                    for (int c = 0; c < 3; ++c) {
                        const size_t xi = ((size_t)c * 512 + gy) * 512 + gx;
                        const float xv = xorig[xi];
                        outE[xi] = xv + om * (xv * xv - xv);
                    }
                }
            } else {
                ushortT* outP = outP0 + (size_t)z * PSTR;
                #pragma unroll
                for (int mt = 0; mt < MT; ++mt) {
                    const size_t off = ((size_t)(gy + 1) * 514 + gx + 1) * 32 + 16 * mt + 4 * slot;
                    float v[4];
                    #pragma unroll
                    for (int reg = 0; reg < 4; ++reg)
                        v[reg] = acc[rr][mt][reg] + bptr[16 * mt + 4 * slot + reg];
                    if constexpr (EPI == 0) {
                        #pragma unroll
                        for (int reg = 0; reg < 4; ++reg) v[reg] = fmaxf(v[reg], 0.f);
                    } else if constexpr (EPI == 2) {
                        // residual f_deco read from LDS (staged input = f_deco)
                        const int prow = r2 + rr + 1;
                        const int lxr = xw + l15 + 1;
                        const int vsr = (lxr + (lxr >> 2)) & 3;
                        const int oo = (2 * mt + (slot >> 1)) ^ vsr;
                        const uint2 din = *(const uint2*)(sb + (prow * RSX + lxr) * 64 + (oo << 4) + ((slot & 1) << 3));
                        const float* gamma = gamma0 + 32 * z;
                        const float* beta  = beta0 + 32 * z;
                        const int cb = 16 * mt + 4 * slot;
                        v[0] = bf2f((unsigned short)(din.x & 0xffff)) + gamma[cb + 0] * v[0] + beta[cb + 0];
                        v[1] = bf2f((unsigned short)(din.x >> 16))    + gamma[cb + 1] * v[1] + beta[cb + 1];
                        v[2] = bf2f((unsigned short)(din.y & 0xffff)) + gamma[cb + 2] * v[2] + beta[cb + 2];
                        v[3] = bf2f((unsigned short)(din.y >> 16))    + gamma[cb + 3] * v[3] + beta[cb + 3];
                    }
                    *(uint2*)(outP + off) = make_uint2(pack2(v[0], v[1]), pack2(v[2], v[3]));
                }
            }
        }
    }
}

// ---------------------------------------------------------------------------
// Haar DWT (all 4 batches)
// ---------------------------------------------------------------------------
__global__ __launch_bounds__(TPB) void dwt_k(
    const float* __restrict__ x, float* __restrict__ haarA, float* __restrict__ hf)
{
    const int idx = blockIdx.x * TPB + threadIdx.x;
    if (idx >= 4 * 256 * 256) return;
    const int xo = idx & 255;
    const int yo = (idx >> 8) & 255;
    const int b  = idx >> 16;
    #pragma unroll
    for (int c = 0; c < 3; ++c) {
        const float* p = x + (((size_t)b * 3 + c) * 512 + 2 * yo) * 512 + 2 * xo;
        const float a = p[0], bb = p[1], cc = p[512], d = p[513];
        haarA[(((size_t)b * 3 + c) * 256 + yo) * 256 + xo] = 0.5f * (a + bb + cc + d);
        hf[(((size_t)b * 9 + 0 + c) * 256 + yo) * 256 + xo] = 0.5f * (a + bb - cc - d);
        hf[(((size_t)b * 9 + 3 + c) * 256 + yo) * 256 + xo] = 0.5f * (a - bb + cc - d);
        hf[(((size_t)b * 9 + 6 + c) * 256 + yo) * 256 + xo] = 0.5f * (a - bb - cc + d);
    }
}

// ---------------------------------------------------------------------------
// Finish channel means from ctlf partials.
// br=0 -> amean (ct: cog 0,1), br=1 -> am0 (lf: cog 2,3).
// ---------------------------------------------------------------------------
__global__ __launch_bounds__(TPB) void meanfin_k(
    const float* __restrict__ part, float* __restrict__ amean, float* __restrict__ am0)
{
    const int br = blockIdx.x;
    const int o = threadIdx.x;                 // z(4) x co(64)
    const int z = o >> 6, co = o & 63;
    const int cog = (br ? 2 : 0) + (co >> 5), c = co & 31;
    const float* p = part + (((size_t)z * 4 + cog) * 256) * 32 + c;
    float s = 0.f;
    for (int j = 0; j < 256; ++j) s += p[j * 32];
    (br ? am0 : amean)[z * 64 + co] = s * (1.f / 65536.f);
}

// ---------------------------------------------------------------------------
// t1->t2->t3 chain, blockIdx.x = b
// ---------------------------------------------------------------------------
__global__ __launch_bounds__(64) void tchain_k(
    const float* __restrict__ amean,
    const float* __restrict__ t1w, const float* __restrict__ t1b,
    const float* __restrict__ t2w, const float* __restrict__ t2b,
    const float* __restrict__ t3w, const float* __restrict__ t3b,
    float* __restrict__ theta)
{
    const int b = blockIdx.x;
    const float* am = amean + b * 64;
    __shared__ float a0[64], a1[64], a2[64];
    const int co = threadIdx.x;
    a0[co] = am[co];
    __syncthreads();
    float s = t1b[co];
    #pragma unroll 8
    for (int ci = 0; ci < 64; ++ci) s = fmaf(t1w[co * 64 + ci], a0[ci], s);
    a1[co] = fmaxf(s, 0.f);
    __syncthreads();
    s = t2b[co];
    #pragma unroll 8
    for (int ci = 0; ci < 64; ++ci) s = fmaf(t2w[co * 64 + ci], a1[ci], s);
    a2[co] = fmaxf(s, 0.f);
    __syncthreads();
    if (co == 0) {
        float v = t3b[0];
        for (int ci = 0; ci < 64; ++ci) v = fmaf(t3w[ci], a2[ci], v);
        theta[b] = 1.f / (1.f + expf(-v));
    }
}

// ---------------------------------------------------------------------------
// wave-per-output FC. ACT 0 relu, 1 sigmoid, 2 tanh.
// ---------------------------------------------------------------------------
template<int ACT>
__global__ __launch_bounds__(TPB) void fcw_k(
    const float* __restrict__ in, const float* __restrict__ w,
    const float* __restrict__ bias, float* __restrict__ out, int K, int N)
{
    const int lane = threadIdx.x & 63, wv = threadIdx.x >> 6;
    const int idx = blockIdx.x * 4 + wv;
    if (idx >= 4 * N) return;
    const int b = idx / N, co = idx % N;
    float s = 0.f;
    for (int k = lane * 4; k < K; k += 256) {
        const float4 wv4 = *(const float4*)(w + (size_t)co * K + k);
        const float4 iv  = *(const float4*)(in + (size_t)b * K + k);
        s += wv4.x * iv.x + wv4.y * iv.y + wv4.z * iv.z + wv4.w * iv.w;
    }
    #pragma unroll
    for (int o = 32; o > 0; o >>= 1) s += __shfl_xor(s, o, 64);
    if (lane == 0) {
        s += bias[co];
        if (ACT == 0) s = fmaxf(s, 0.f);
        else if (ACT == 1) s = 1.f / (1.f + expf(-s));
        else s = tanhf(s);
        out[(size_t)b * N + co] = s;
    }
}

// ---------------------------------------------------------------------------
extern "C" void kernel_launch(void* const* d_in, const int* in_sizes, int n_in,
                              void* d_out, int out_size, void* d_ws, size_t ws_size,
                              hipStream_t stream)
{
    const float* x      = (const float*)d_in[0];
    const float* cdc_w  = (const float*)d_in[11];
    const float* t1_w   = (const float*)d_in[14];
    const float* t1_b   = (const float*)d_in[15];
    const float* t2_w   = (const float*)d_in[16];
    const float* t2_b   = (const float*)d_in[17];
    const float* t3_w   = (const float*)d_in[18];
    const float* t3_b   = (const float*)d_in[19];
    const float* fc1_w  = (const float*)d_in[22];
    const float* fc1_b  = (const float*)d_in[23];
    const float* fc2_w  = (const float*)d_in[24];
    const float* fc2_b  = (const float*)d_in[25];
    const float* fc3_w  = (const float*)d_in[26];
    const float* fc3_b  = (const float*)d_in[27];
    const float* g_w    = (const float*)d_in[28];
    const float* g_b    = (const float*)d_in[29];
    const float* be_w   = (const float*)d_in[30];
    const float* be_b   = (const float*)d_in[31];

    float* out = (float*)d_out;

    // workspace layout (haarA/hf alias B2; consumed before B2's first write)
    ushortT* A2 = (ushortT*)d_ws;                  // 4 x 16.9 MB
    ushortT* B2 = A2 + 4 * PSTR;                   // 4 x 16.9 MB
    float* haarA = (float*)B2;                     // (4,3,256,256) phase A only
    float* hf    = haarA + 786432;                 // (4,9,256,256) phase A only
    float* part  = (float*)(B2 + 4 * PSTR);        // 4z x 4cog x 256 x 32 = 131072
    float* amean = part + 131072;                  // 256
    float* am0   = amean + 256;                    // 256
    float* am1   = am0 + 256;                      // 2048
    float* am2   = am1 + 2048;
    float* am3   = am2 + 2048;
    float* theta = am3 + 2048;                     // 4
    float* gamma = theta + 4;                      // 128 [4][32]
    float* beta  = gamma + 128;                    // 128
    short* wpack = (short*)(beta + 128);           // 16 x 10240 shorts
    const size_t need_bytes = (size_t)((char*)(wpack + 16 * 10240) - (char*)d_ws);
    if (ws_size < need_bytes) return;

    const dim3 blk(TPB);

    // --- phase A ---
    dwt_k<<<dim3((4 * 256 * 256 + TPB - 1) / TPB), blk, 0, stream>>>(x, haarA, hf);
    packall_k<<<dim3(12), dim3(64), 0, stream>>>(
        (const float*)d_in[1], (const float*)d_in[2], (const float*)d_in[3], (const float*)d_in[4],
        (const float*)d_in[5], (const float*)d_in[6], (const float*)d_in[7], (const float*)d_in[8],
        (const float*)d_in[9], (const float*)d_in[10], (const float*)d_in[32], (const float*)d_in[33],
        (const float*)d_in[34], (const float*)d_in[35], (const float*)d_in[36], (const float*)d_in[37],
        (const float*)d_in[12], (const float*)d_in[13], (const float*)d_in[20], (const float*)d_in[21],
        wpack);

    // fused ct+lf conv -> channel partials (one dispatch)
    ctlf_k<<<dim3(256, 4, 4), blk, 0, stream>>>(hf, haarA, wpack + 8 * 10240, part);

    // haarA/hf consumed -> zero halos of all 8 padded buffers
    zero_k<<<dim3((8 * 32832 + TPB - 1) / TPB), blk, 0, stream>>>((unsigned int*)A2, (unsigned int*)B2);

    meanfin_k<<<dim3(2), blk, 0, stream>>>(part, amean, am0);
    tchain_k<<<dim3(4), dim3(64), 0, stream>>>(amean, t1_w, t1_b, t2_w, t2_b, t3_w, t3_b, theta);
    fcw_k<0><<<dim3(512), blk, 0, stream>>>(am0, fc1_w, fc1_b, am1, 64, 512);
    fcw_k<0><<<dim3(512), blk, 0, stream>>>(am1, fc2_w, fc2_b, am2, 512, 512);
    fcw_k<1><<<dim3(512), blk, 0, stream>>>(am2, fc3_w, fc3_b, am3, 512, 512);
    fcw_k<1><<<dim3(32), blk, 0, stream>>>(am3, g_w, g_b, gamma, 512, 32);
    fcw_k<2><<<dim3(32), blk, 0, stream>>>(am3, be_w, be_b, beta, 512, 32);
    packcdc_k<<<dim3(4), dim3(64), 0, stream>>>(cdc_w, theta, wpack);

    // --- heavy chain: enc1n + 8 DMA-staged dconv64 dispatches ---
    const dim3 gN(1024, 1, 4);
    float* outM = out + (size_t)4 * 3 * HW;

    enc1n_k<<<gN, blk, 0, stream>>>(x, wpack, A2);
    dconv64_k<0><<<gN, blk, 0, stream>>>(A2, wpack + 1 * 10240, 0, B2, nullptr, nullptr, nullptr, nullptr, nullptr);
    dconv64_k<0><<<gN, blk, 0, stream>>>(B2, wpack + 2 * 10240, 0, A2, nullptr, nullptr, nullptr, nullptr, nullptr);
    dconv64_k<0><<<gN, blk, 0, stream>>>(A2, wpack + 3 * 10240, 0, B2, nullptr, nullptr, nullptr, nullptr, nullptr);
    dconv64_k<0><<<gN, blk, 0, stream>>>(B2, wpack + 4 * 10240, 0, A2, nullptr, nullptr, nullptr, nullptr, nullptr);
    // cdc (theta folded per batch): A2 -> B2 = f_deco
    dconv64_k<0><<<gN, blk, 0, stream>>>(A2, wpack + 12 * 10240, 10240, B2, nullptr, nullptr, nullptr, nullptr, nullptr);
    // res: B2 -> A2 (residual from LDS)
    dconv64_k<2><<<gN, blk, 0, stream>>>(B2, wpack + 5 * 10240, 0, A2, gamma, beta, nullptr, nullptr, nullptr);
    // d1: A2 -> B2
    dconv64_k<0><<<gN, blk, 0, stream>>>(A2, wpack + 6 * 10240, 0, B2, nullptr, nullptr, nullptr, nullptr, nullptr);
    // d2 + tanh + enhance -> outputs
    dconv64_k<3><<<gN, blk, 0, stream>>>(B2, wpack + 7 * 10240, 0, nullptr, nullptr, nullptr, x, out, outM);
}

// Round 12
// 364.723 us; speedup vs baseline: 1.3677x; 1.0982x over previous
//
#include <hip/hip_runtime.h>
#include <hip/hip_bf16.h>
#include <cmath>

#define TPB 256

typedef __attribute__((ext_vector_type(8))) short s16x8;
typedef __attribute__((ext_vector_type(4))) float f32x4;
typedef unsigned short ushortT;

constexpr long long PSTR = 8454272;   // 514*514*32 ushorts per padded image
constexpr int HW = 512 * 512;

static __device__ __forceinline__ short f2bf(float f) {
    union { __hip_bfloat16 h; short s; } u;
    u.h = __float2bfloat16(f);
    return u.s;
}
static __device__ __forceinline__ float bf2f(unsigned short u) {
    union { unsigned int i; float f; } v;
    v.i = ((unsigned int)u) << 16;
    return v.f;
}
static __device__ __forceinline__ unsigned int pack2(float a, float b) {
    return (unsigned int)(unsigned short)f2bf(a) | ((unsigned int)(unsigned short)f2bf(b) << 16);
}

// global->LDS DMA, 16B per lane; lds dest = wave-uniform base + lane*16
#define GLOAD_LDS16(gp, lp) \
    __builtin_amdgcn_global_load_lds((const __attribute__((address_space(1))) void*)(gp), \
                                     (__attribute__((address_space(3))) void*)(lp), 16, 0, 0)

// ---------------------------------------------------------------------------
// Weight pack body. slot stride 10240 shorts; bias fp32 @ short-offset 9216.
// Packed ci position = ci_off + source ci. cdc fold: center tap -= theta*sum.
// ---------------------------------------------------------------------------
static __device__ void pack_body(const float* w, const float* bias, const float* theta,
                                 short* dst, int CO, int CI_src, int ci_off, int cog, int l)
{
    const int l15 = l & 15, sl = l >> 4;
    for (int t = 0; t < 9; ++t) {
        for (int mt = 0; mt < 2; ++mt) {
            const int co = cog * 32 + 16 * mt + l15;
            s16x8 p;
            #pragma unroll
            for (int i = 0; i < 8; ++i) {
                const int pci = 8 * sl + i;
                float val = 0.f;
                if (co < CO && pci >= ci_off && pci < ci_off + CI_src) {
                    const int ci = pci - ci_off;
                    val = w[((size_t)co * CI_src + ci) * 9 + t];
                    if (theta && t == 4) {
                        float s = 0.f;
                        for (int tt = 0; tt < 9; ++tt) s += w[((size_t)co * CI_src + ci) * 9 + tt];
                        val -= theta[0] * s;
                    }
                }
                p[i] = f2bf(val);
            }
            *(s16x8*)(dst + ((size_t)(t * 2 + mt) * 64 + l) * 8) = p;
        }
    }
    if (l < 32) {
        const int co = cog * 32 + l;
        ((float*)(dst + 9216))[l] = (bias && co < CO) ? bias[co] : 0.f;
    }
}

__global__ __launch_bounds__(64) void packall_k(
    const float* e1w, const float* e1b, const float* e2w, const float* e2b,
    const float* e3w, const float* e3b, const float* e4w, const float* e4b,
    const float* e5w, const float* e5b, const float* resw, const float* resb,
    const float* d1w, const float* d1b, const float* d2w, const float* d2b,
    const float* ctw, const float* ctb, const float* lfw, const float* lfb,
    short* wpack)
{
    const int s = blockIdx.x;
    const float *w, *b;
    int CO = 32, CI = 32, coff = 0, cog = 0;
    switch (s) {
        case 0: w = e1w; b = e1b; CI = 3; break;
        case 1: w = e2w; b = e2b; break;
        case 2: w = e3w; b = e3b; break;
        case 3: w = e4w; b = e4b; break;
        case 4: w = e5w; b = e5b; break;
        case 5: w = resw; b = resb; break;
        case 6: w = d1w; b = d1b; break;
        case 7: w = d2w; b = d2b; CO = 1; break;
        case 8: case 9: w = ctw; b = ctb; CO = 64; CI = 9; cog = s - 8; break;
        default: w = lfw; b = lfb; CO = 64; CI = 3; coff = 9; cog = s - 10; break;
    }
    pack_body(w, b, nullptr, wpack + (size_t)s * 10240, CO, CI, coff, cog, threadIdx.x);
}

__global__ __launch_bounds__(64) void packcdc_k(
    const float* cdcw, const float* theta, short* wpack)
{
    const int b = blockIdx.x;
    pack_body(cdcw, nullptr, theta + b, wpack + (size_t)(12 + b) * 10240, 32, 32, 0, 0, threadIdx.x);
}

// ---------------------------------------------------------------------------
// zero halo rings of 8 padded NHWC buffers (A2 z0..3, B2 z0..3)
// ---------------------------------------------------------------------------
__global__ __launch_bounds__(TPB) void zero_k(unsigned int* A2u, unsigned int* B2u)
{
    const int idx = blockIdx.x * TPB + threadIdx.x;
    if (idx >= 8 * 32832) return;
    const int q = idx / 32832, r = idx % 32832;
    unsigned int* P = (q < 4 ? A2u : B2u) + (size_t)(q & 3) * 4227136;
    const int RSU = 514 * 16;
    int off;
    if (r < 8224)       off = r;
    else if (r < 16448) off = 513 * RSU + (r - 8224);
    else if (r < 24640) { int u = r - 16448; off = (1 + (u >> 4)) * RSU + (u & 15); }
    else                { int u = r - 24640; off = (1 + (u >> 4)) * RSU + 513 * 16 + (u & 15); }
    P[off] = 0u;
}

// ---------------------------------------------------------------------------
// Fused ct+lf conv -> per-block channel partial sums (unchanged from r11).
// ---------------------------------------------------------------------------
__global__ __launch_bounds__(TPB) void ctlf_k(
    const float* __restrict__ hf0, const float* __restrict__ haarA0,
    const short* __restrict__ wpack8, float* __restrict__ part)
{
    constexpr int RSX = 66;
    constexpr int ROWB = RSX * 64;
    __shared__ s16x8 lds_t[6 * RSX * 4];
    __shared__ float s_red[4][32];
    char* sb = (char*)lds_t;

    const int z = blockIdx.z, cog = blockIdx.y;
    const int bid = blockIdx.x;
    const int x0 = (bid & 3) * 64, y0 = (bid >> 2) * 4;
    const int tid = threadIdx.x, lane = tid & 63, wv = tid >> 6;
    const int l15 = lane & 15, slot = lane >> 4;

    const short* wslot = wpack8 + (size_t)cog * 10240;
    const float* hfz = hf0 + (size_t)z * 9 * 65536;
    const float* haz = haarA0 + (size_t)z * 3 * 65536;

    s16x8 wf[9][2];
    #pragma unroll
    for (int t = 0; t < 9; ++t)
        #pragma unroll
        for (int mt = 0; mt < 2; ++mt)
            wf[t][mt] = *(const s16x8*)(wslot + ((size_t)(t * 2 + mt) * 64 + lane) * 8);

    #pragma unroll
    for (int j = 0; j < 7; ++j) {
        const int p = j * 256 + tid;
        if (p < 1584) {
            const int row = p / 264;
            const int rem = p - row * 264;
            const int lx = rem >> 2, osl = rem & 3;
            const int o = osl ^ ((lx + (lx >> 2)) & 3);
            s16x8 pk;
            #pragma unroll
            for (int i = 0; i < 8; ++i) pk[i] = 0;
            const int sy = y0 + row - 1, sx = x0 + lx - 1;
            if (o < 2 && sy >= 0 && sy < 256 && sx >= 0 && sx < 256) {
                const size_t base = (size_t)sy * 256 + sx;
                if (o == 0) {
                    #pragma unroll
                    for (int i = 0; i < 8; ++i)
                        pk[i] = f2bf(hfz[(size_t)i * 65536 + base]);
                } else {
                    pk[0] = f2bf(hfz[(size_t)8 * 65536 + base]);
                    pk[1] = f2bf(haz[base]);
                    pk[2] = f2bf(haz[(size_t)65536 + base]);
                    pk[3] = f2bf(haz[(size_t)2 * 65536 + base]);
                }
            }
            *(s16x8*)(sb + p * 16) = pk;
        }
    }
    __syncthreads();

    const int xw = 16 * wv;
    int roff[3];
    #pragma unroll
    for (int dx = 0; dx < 3; ++dx) {
        const int lx = xw + dx + l15;
        const int vs = (lx + (lx >> 2)) & 3;
        roff[dx] = lx * 64 + ((slot ^ vs) << 4);
    }
    const float* bptr = (const float*)(wslot + 9216);

    float ps[2][4];
    #pragma unroll
    for (int mt = 0; mt < 2; ++mt)
        #pragma unroll
        for (int reg = 0; reg < 4; ++reg) ps[mt][reg] = 0.f;

    #pragma unroll
    for (int r2 = 0; r2 < 4; r2 += 2) {
        f32x4 acc[2][2];
        #pragma unroll
        for (int a = 0; a < 2; ++a)
            #pragma unroll
            for (int b = 0; b < 2; ++b)
                #pragma unroll
                for (int e = 0; e < 4; ++e) acc[a][b][e] = 0.f;

        #pragma unroll
        for (int dy = 0; dy < 3; ++dy) {
            const int rb0 = (r2 + dy) * ROWB;
            #pragma unroll
            for (int dx = 0; dx < 3; ++dx) {
                const int tap = dy * 3 + dx;
                const s16x8 b0 = *(const s16x8*)(sb + rb0 + roff[dx]);
                const s16x8 b1 = *(const s16x8*)(sb + rb0 + ROWB + roff[dx]);
                #pragma unroll
                for (int mt = 0; mt < 2; ++mt) {
                    acc[0][mt] = __builtin_amdgcn_mfma_f32_16x16x32_bf16(wf[tap][mt], b0, acc[0][mt], 0, 0, 0);
                    acc[1][mt] = __builtin_amdgcn_mfma_f32_16x16x32_bf16(wf[tap][mt], b1, acc[1][mt], 0, 0, 0);
                }
            }
        }

        #pragma unroll
        for (int rr = 0; rr < 2; ++rr)
            #pragma unroll
            for (int mt = 0; mt < 2; ++mt)
                #pragma unroll
                for (int reg = 0; reg < 4; ++reg)
                    ps[mt][reg] += fmaxf(acc[rr][mt][reg] + bptr[16 * mt + 4 * slot + reg], 0.f);
    }

    #pragma unroll
    for (int mt = 0; mt < 2; ++mt)
        #pragma unroll
        for (int reg = 0; reg < 4; ++reg) {
            #pragma unroll
            for (int o = 1; o < 16; o <<= 1)
                ps[mt][reg] += __shfl_xor(ps[mt][reg], o, 64);
        }
    #pragma unroll
    for (int mt = 0; mt < 2; ++mt)
        #pragma unroll
        for (int reg = 0; reg < 4; ++reg)
            if (l15 == mt * 4 + reg)
                s_red[wv][16 * mt + 4 * slot + reg] = ps[mt][reg];
    __syncthreads();
    if (tid < 32) {
        const float s = s_red[0][tid] + s_red[1][tid] + s_red[2][tid] + s_red[3][tid];
        part[(((size_t)z * 4 + cog) * 256 + bid) * 32 + tid] = s;
    }
}

// ---------------------------------------------------------------------------
// enc1: narrow 64px x 4row conv, fp32 NCHW 3-ch input -> padded NHWC bf16.
// ---------------------------------------------------------------------------
__global__ __launch_bounds__(TPB) void enc1n_k(
    const float* __restrict__ x0p, const short* __restrict__ wslot,
    ushortT* __restrict__ outP0)
{
    constexpr int RSX = 66;
    constexpr int ROWB = RSX * 64;
    __shared__ s16x8 lds_t[6 * RSX * 4];
    char* sb = (char*)lds_t;

    const int z = blockIdx.z;
    const float* xin = x0p + (size_t)z * 3 * HW;

    const int tid = threadIdx.x, lane = tid & 63, wv = tid >> 6;
    const int bid = blockIdx.x;
    const int swz = (bid & 7) * 128 + (bid >> 3);
    const int x0 = (swz & 7) * 64, y0 = (swz >> 3) * 4;
    const int l15 = lane & 15, slot = lane >> 4;

    s16x8 wf[9][2];
    #pragma unroll
    for (int t = 0; t < 9; ++t)
        #pragma unroll
        for (int mt = 0; mt < 2; ++mt)
            wf[t][mt] = *(const s16x8*)(wslot + ((size_t)(t * 2 + mt) * 64 + lane) * 8);

    #pragma unroll
    for (int j = 0; j < 7; ++j) {
        const int p = j * 256 + tid;
        if (p < 1584) {
            const int row = p / 264;
            const int rem = p - row * 264;
            const int lx = rem >> 2, osl = rem & 3;
            const int o = osl ^ ((lx + (lx >> 2)) & 3);
            s16x8 pk;
            #pragma unroll
            for (int i = 0; i < 8; ++i) pk[i] = 0;
            if (o == 0) {
                const int gy = y0 + row - 1;
                const int gx = x0 + lx - 1;
                if (gy >= 0 && gy < 512 && gx >= 0 && gx < 512) {
                    #pragma unroll
                    for (int c = 0; c < 3; ++c)
                        pk[c] = f2bf(xin[((size_t)c * 512 + gy) * 512 + gx]);
                }
            }
            *(s16x8*)(sb + p * 16) = pk;
        }
    }
    __syncthreads();

    const int xw = 16 * wv;
    int roff[3];
    #pragma unroll
    for (int dx = 0; dx < 3; ++dx) {
        const int lx = xw + dx + l15;
        const int vs = (lx + (lx >> 2)) & 3;
        roff[dx] = lx * 64 + ((slot ^ vs) << 4);
    }
    const float* bptr = (const float*)(wslot + 9216);
    ushortT* outP = outP0 + (size_t)z * PSTR;

    #pragma unroll
    for (int r2 = 0; r2 < 4; r2 += 2) {
        f32x4 acc[2][2];
        #pragma unroll
        for (int a = 0; a < 2; ++a)
            #pragma unroll
            for (int b = 0; b < 2; ++b)
                #pragma unroll
                for (int e = 0; e < 4; ++e) acc[a][b][e] = 0.f;

        #pragma unroll
        for (int dy = 0; dy < 3; ++dy) {
            const int rb0 = (r2 + dy) * ROWB;
            #pragma unroll
            for (int dx = 0; dx < 3; ++dx) {
                const int tap = dy * 3 + dx;
                const s16x8 b0 = *(const s16x8*)(sb + rb0 + roff[dx]);
                const s16x8 b1 = *(const s16x8*)(sb + rb0 + ROWB + roff[dx]);
                #pragma unroll
                for (int mt = 0; mt < 2; ++mt) {
                    acc[0][mt] = __builtin_amdgcn_mfma_f32_16x16x32_bf16(wf[tap][mt], b0, acc[0][mt], 0, 0, 0);
                    acc[1][mt] = __builtin_amdgcn_mfma_f32_16x16x32_bf16(wf[tap][mt], b1, acc[1][mt], 0, 0, 0);
                }
            }
        }

        #pragma unroll
        for (int rr = 0; rr < 2; ++rr) {
            const int gy = y0 + r2 + rr;
            const int gx = x0 + xw + l15;
            #pragma unroll
            for (int mt = 0; mt < 2; ++mt) {
                const size_t off = ((size_t)(gy + 1) * 514 + gx + 1) * 32 + 16 * mt + 4 * slot;
                float v[4];
                #pragma unroll
                for (int reg = 0; reg < 4; ++reg)
                    v[reg] = fmaxf(acc[rr][mt][reg] + bptr[16 * mt + 4 * slot + reg], 0.f);
                *(uint2*)(outP + off) = make_uint2(pack2(v[0], v[1]), pack2(v[2], v[3]));
            }
        }
    }
}

// ---------------------------------------------------------------------------
// Pipelined double-buffered DMA conv on padded NHWC bf16.
// Block = 4 y-consecutive 64px x 4row tiles. Two 25.3 KB LDS buffers
// (50.7 KB -> 3 blocks/CU). Per tile t: bar(drains DMA t) -> issue DMA t+1
// into buf[(t+1)&1] -> compute t. DMA holds no registers -> no spill.
// EPI: 0 relu | 2 res (residual from LDS) | 3 d2+enhance.
// ---------------------------------------------------------------------------
template<int EPI>
__global__ __launch_bounds__(TPB) void dconv64p_k(
    const ushortT* __restrict__ inP0, const short* __restrict__ wbase, int wstr,
    ushortT* __restrict__ outP0,
    const float* __restrict__ gamma0, const float* __restrict__ beta0,
    const float* __restrict__ xorig0, float* __restrict__ outE0, float* __restrict__ outM0)
{
    constexpr int MT = (EPI == 3) ? 1 : 2;
    constexpr int RSX = 66;
    constexpr int ROWB = RSX * 64;
    constexpr int BUFB = 6 * RSX * 64;      // 25,344 B per buffer
    __shared__ s16x8 lds_t[2 * 6 * RSX * 4];  // 50,688 B
    char* sbase = (char*)lds_t;

    const int z = blockIdx.z;
    const ushortT* inP = inP0 + (size_t)z * PSTR;
    const short* wslot = wbase + (size_t)z * wstr;

    const int tid = threadIdx.x, lane = tid & 63, wv = tid >> 6;
    const int bid = blockIdx.x;                 // 0..255
    // XCD-contiguous: xcd = bid&7 owns rows [64*xcd, 64*xcd+64)
    const int xcd = bid & 7, idx = bid >> 3;    // idx 0..31
    const int x0 = (idx & 7) * 64;
    const int yband = xcd * 4 + (idx >> 3);     // 0..31
    const int l15 = lane & 15, slot = lane >> 4;

    s16x8 wf[9][MT];
    #pragma unroll
    for (int t = 0; t < 9; ++t)
        #pragma unroll
        for (int mt = 0; mt < MT; ++mt)
            wf[t][mt] = *(const s16x8*)(wslot + ((size_t)(t * 2 + mt) * 64 + lane) * 8);

    const int xw = 16 * wv;
    int roff[3];
    #pragma unroll
    for (int dx = 0; dx < 3; ++dx) {
        const int lx = xw + dx + l15;
        const int vs = (lx + (lx >> 2)) & 3;
        roff[dx] = lx * 64 + ((slot ^ vs) << 4);
    }
    const float* bptr = (const float*)(wslot + 9216);

    // stage tile (y0 = yband*16 + 4*t) into buffer b
    auto stage = [&](int t, int b) {
        const int y0 = yband * 16 + 4 * t;
        char* sb = sbase + b * BUFB;
        #pragma unroll
        for (int j = 0; j < 6; ++j) {
            const int p = j * 256 + tid;
            const int row = p / 264;
            const int rem = p - row * 264;
            const int lx = rem >> 2, osl = rem & 3;
            const int o = osl ^ ((lx + (lx >> 2)) & 3);
            const ushortT* gp = inP + ((size_t)(y0 + row) * 514 + x0 + lx) * 32 + o * 8;
            GLOAD_LDS16(gp, sb + (size_t)(j * 256 + wv * 64) * 16);
        }
        if (tid < 48) {
            const int p = 1536 + tid;
            const int row = p / 264;
            const int rem = p - row * 264;
            const int lx = rem >> 2, osl = rem & 3;
            const int o = osl ^ ((lx + (lx >> 2)) & 3);
            const ushortT* gp = inP + ((size_t)(y0 + row) * 514 + x0 + lx) * 32 + o * 8;
            GLOAD_LDS16(gp, sb + (size_t)1536 * 16);
        }
    };

    stage(0, 0);   // prologue

    #pragma unroll 1
    for (int t = 0; t < 4; ++t) {
        __syncthreads();             // drains DMA for tile t; syncs buffer reuse
        if (t < 3) stage(t + 1, (t + 1) & 1);   // overlaps with compute below
        char* sb = sbase + (t & 1) * BUFB;
        const int y0t = yband * 16 + 4 * t;

        #pragma unroll
        for (int r2 = 0; r2 < 4; r2 += 2) {
            f32x4 acc[2][MT];
            #pragma unroll
            for (int a = 0; a < 2; ++a)
                #pragma unroll
                for (int b = 0; b < MT; ++b)
                    #pragma unroll
                    for (int e = 0; e < 4; ++e) acc[a][b][e] = 0.f;

            #pragma unroll
            for (int dy = 0; dy < 3; ++dy) {
                const int rb0 = (r2 + dy) * ROWB;
                #pragma unroll
                for (int dx = 0; dx < 3; ++dx) {
                    const int tap = dy * 3 + dx;
                    const s16x8 b0 = *(const s16x8*)(sb + rb0 + roff[dx]);
                    const s16x8 b1 = *(const s16x8*)(sb + rb0 + ROWB + roff[dx]);
                    #pragma unroll
                    for (int mt = 0; mt < MT; ++mt) {
                        acc[0][mt] = __builtin_amdgcn_mfma_f32_16x16x32_bf16(wf[tap][mt], b0, acc[0][mt], 0, 0, 0);
                        acc[1][mt] = __builtin_amdgcn_mfma_f32_16x16x32_bf16(wf[tap][mt], b1, acc[1][mt], 0, 0, 0);
                    }
                }
            }

            #pragma unroll
            for (int rr = 0; rr < 2; ++rr) {
                const int gy = y0t + r2 + rr;
                const int gx = x0 + xw + l15;
                if constexpr (EPI == 3) {
                    if (slot == 0) {
                        const float* xorig = xorig0 + (size_t)z * 3 * HW;
                        float* outE = outE0 + (size_t)z * 3 * HW;
                        float* outM = outM0 + (size_t)z * HW;
                        const float om = tanhf(acc[rr][0][0] + bptr[0]);
                        outM[(size_t)gy * 512 + gx] = om;
                        #pragma unroll
                        for (int c = 0; c < 3; ++c) {
                            const size_t xi = ((size_t)c * 512 + gy) * 512 + gx;
                            const float xv = xorig[xi];
                            outE[xi] = xv + om * (xv * xv - xv);
                        }
                    }
                } else {
                    ushortT* outP = outP0 + (size_t)z * PSTR;
                    #pragma unroll
                    for (int mt = 0; mt < MT; ++mt) {
                        const size_t off = ((size_t)(gy + 1) * 514 + gx + 1) * 32 + 16 * mt + 4 * slot;
                        float v[4];
                        #pragma unroll
                        for (int reg = 0; reg < 4; ++reg)
                            v[reg] = acc[rr][mt][reg] + bptr[16 * mt + 4 * slot + reg];
                        if constexpr (EPI == 0) {
                            #pragma unroll
                            for (int reg = 0; reg < 4; ++reg) v[reg] = fmaxf(v[reg], 0.f);
                        } else if constexpr (EPI == 2) {
                            // residual f_deco from this tile's LDS buffer
                            const int prow = r2 + rr + 1;
                            const int lxr = xw + l15 + 1;
                            const int vsr = (lxr + (lxr >> 2)) & 3;
                            const int oo = (2 * mt + (slot >> 1)) ^ vsr;
                            const uint2 din = *(const uint2*)(sb + (prow * RSX + lxr) * 64 + (oo << 4) + ((slot & 1) << 3));
                            const float* gamma = gamma0 + 32 * z;
                            const float* beta  = beta0 + 32 * z;
                            const int cb = 16 * mt + 4 * slot;
                            v[0] = bf2f((unsigned short)(din.x & 0xffff)) + gamma[cb + 0] * v[0] + beta[cb + 0];
                            v[1] = bf2f((unsigned short)(din.x >> 16))    + gamma[cb + 1] * v[1] + beta[cb + 1];
                            v[2] = bf2f((unsigned short)(din.y & 0xffff)) + gamma[cb + 2] * v[2] + beta[cb + 2];
                            v[3] = bf2f((unsigned short)(din.y >> 16))    + gamma[cb + 3] * v[3] + beta[cb + 3];
                        }
                        *(uint2*)(outP + off) = make_uint2(pack2(v[0], v[1]), pack2(v[2], v[3]));
                    }
                }
            }
        }
    }
}

// ---------------------------------------------------------------------------
// Haar DWT (all 4 batches)
// ---------------------------------------------------------------------------
__global__ __launch_bounds__(TPB) void dwt_k(
    const float* __restrict__ x, float* __restrict__ haarA, float* __restrict__ hf)
{
    const int idx = blockIdx.x * TPB + threadIdx.x;
    if (idx >= 4 * 256 * 256) return;
    const int xo = idx & 255;
    const int yo = (idx >> 8) & 255;
    const int b  = idx >> 16;
    #pragma unroll
    for (int c = 0; c < 3; ++c) {
        const float* p = x + (((size_t)b * 3 + c) * 512 + 2 * yo) * 512 + 2 * xo;
        const float a = p[0], bb = p[1], cc = p[512], d = p[513];
        haarA[(((size_t)b * 3 + c) * 256 + yo) * 256 + xo] = 0.5f * (a + bb + cc + d);
        hf[(((size_t)b * 9 + 0 + c) * 256 + yo) * 256 + xo] = 0.5f * (a + bb - cc - d);
        hf[(((size_t)b * 9 + 3 + c) * 256 + yo) * 256 + xo] = 0.5f * (a - bb + cc - d);
        hf[(((size_t)b * 9 + 6 + c) * 256 + yo) * 256 + xo] = 0.5f * (a - bb - cc + d);
    }
}

// ---------------------------------------------------------------------------
// Finish channel means from ctlf partials.
// ---------------------------------------------------------------------------
__global__ __launch_bounds__(TPB) void meanfin_k(
    const float* __restrict__ part, float* __restrict__ amean, float* __restrict__ am0)
{
    const int br = blockIdx.x;
    const int o = threadIdx.x;
    const int z = o >> 6, co = o & 63;
    const int cog = (br ? 2 : 0) + (co >> 5), c = co & 31;
    const float* p = part + (((size_t)z * 4 + cog) * 256) * 32 + c;
    float s = 0.f;
    for (int j = 0; j < 256; ++j) s += p[j * 32];
    (br ? am0 : amean)[z * 64 + co] = s * (1.f / 65536.f);
}

// ---------------------------------------------------------------------------
// t1->t2->t3 chain, blockIdx.x = b
// ---------------------------------------------------------------------------
__global__ __launch_bounds__(64) void tchain_k(
    const float* __restrict__ amean,
    const float* __restrict__ t1w, const float* __restrict__ t1b,
    const float* __restrict__ t2w, const float* __restrict__ t2b,
    const float* __restrict__ t3w, const float* __restrict__ t3b,
    float* __restrict__ theta)
{
    const int b = blockIdx.x;
    const float* am = amean + b * 64;
    __shared__ float a0[64], a1[64], a2[64];
    const int co = threadIdx.x;
    a0[co] = am[co];
    __syncthreads();
    float s = t1b[co];
    #pragma unroll 8
    for (int ci = 0; ci < 64; ++ci) s = fmaf(t1w[co * 64 + ci], a0[ci], s);
    a1[co] = fmaxf(s, 0.f);
    __syncthreads();
    s = t2b[co];
    #pragma unroll 8
    for (int ci = 0; ci < 64; ++ci) s = fmaf(t2w[co * 64 + ci], a1[ci], s);
    a2[co] = fmaxf(s, 0.f);
    __syncthreads();
    if (co == 0) {
        float v = t3b[0];
        for (int ci = 0; ci < 64; ++ci) v = fmaf(t3w[ci], a2[ci], v);
        theta[b] = 1.f / (1.f + expf(-v));
    }
}

// ---------------------------------------------------------------------------
// wave-per-output FC. ACT 0 relu, 1 sigmoid, 2 tanh.
// ---------------------------------------------------------------------------
template<int ACT>
__global__ __launch_bounds__(TPB) void fcw_k(
    const float* __restrict__ in, const float* __restrict__ w,
    const float* __restrict__ bias, float* __restrict__ out, int K, int N)
{
    const int lane = threadIdx.x & 63, wv = threadIdx.x >> 6;
    const int idx = blockIdx.x * 4 + wv;
    if (idx >= 4 * N) return;
    const int b = idx / N, co = idx % N;
    float s = 0.f;
    for (int k = lane * 4; k < K; k += 256) {
        const float4 wv4 = *(const float4*)(w + (size_t)co * K + k);
        const float4 iv  = *(const float4*)(in + (size_t)b * K + k);
        s += wv4.x * iv.x + wv4.y * iv.y + wv4.z * iv.z + wv4.w * iv.w;
    }
    #pragma unroll
    for (int o = 32; o > 0; o >>= 1) s += __shfl_xor(s, o, 64);
    if (lane == 0) {
        s += bias[co];
        if (ACT == 0) s = fmaxf(s, 0.f);
        else if (ACT == 1) s = 1.f / (1.f + expf(-s));
        else s = tanhf(s);
        out[(size_t)b * N + co] = s;
    }
}

// ---------------------------------------------------------------------------
extern "C" void kernel_launch(void* const* d_in, const int* in_sizes, int n_in,
                              void* d_out, int out_size, void* d_ws, size_t ws_size,
                              hipStream_t stream)
{
    const float* x      = (const float*)d_in[0];
    const float* cdc_w  = (const float*)d_in[11];
    const float* t1_w   = (const float*)d_in[14];
    const float* t1_b   = (const float*)d_in[15];
    const float* t2_w   = (const float*)d_in[16];
    const float* t2_b   = (const float*)d_in[17];
    const float* t3_w   = (const float*)d_in[18];
    const float* t3_b   = (const float*)d_in[19];
    const float* fc1_w  = (const float*)d_in[22];
    const float* fc1_b  = (const float*)d_in[23];
    const float* fc2_w  = (const float*)d_in[24];
    const float* fc2_b  = (const float*)d_in[25];
    const float* fc3_w  = (const float*)d_in[26];
    const float* fc3_b  = (const float*)d_in[27];
    const float* g_w    = (const float*)d_in[28];
    const float* g_b    = (const float*)d_in[29];
    const float* be_w   = (const float*)d_in[30];
    const float* be_b   = (const float*)d_in[31];

    float* out = (float*)d_out;

    // workspace layout (haarA/hf alias B2; consumed before B2's first write)
    ushortT* A2 = (ushortT*)d_ws;                  // 4 x 16.9 MB
    ushortT* B2 = A2 + 4 * PSTR;                   // 4 x 16.9 MB
    float* haarA = (float*)B2;                     // (4,3,256,256) phase A only
    float* hf    = haarA + 786432;                 // (4,9,256,256) phase A only
    float* part  = (float*)(B2 + 4 * PSTR);        // 131072
    float* amean = part + 131072;                  // 256
    float* am0   = amean + 256;                    // 256
    float* am1   = am0 + 256;                      // 2048
    float* am2   = am1 + 2048;
    float* am3   = am2 + 2048;
    float* theta = am3 + 2048;                     // 4
    float* gamma = theta + 4;                      // 128 [4][32]
    float* beta  = gamma + 128;                    // 128
    short* wpack = (short*)(beta + 128);           // 16 x 10240 shorts
    const size_t need_bytes = (size_t)((char*)(wpack + 16 * 10240) - (char*)d_ws);
    if (ws_size < need_bytes) return;

    const dim3 blk(TPB);

    // --- phase A ---
    dwt_k<<<dim3((4 * 256 * 256 + TPB - 1) / TPB), blk, 0, stream>>>(x, haarA, hf);
    packall_k<<<dim3(12), dim3(64), 0, stream>>>(
        (const float*)d_in[1], (const float*)d_in[2], (const float*)d_in[3], (const float*)d_in[4],
        (const float*)d_in[5], (const float*)d_in[6], (const float*)d_in[7], (const float*)d_in[8],
        (const float*)d_in[9], (const float*)d_in[10], (const float*)d_in[32], (const float*)d_in[33],
        (const float*)d_in[34], (const float*)d_in[35], (const float*)d_in[36], (const float*)d_in[37],
        (const float*)d_in[12], (const float*)d_in[13], (const float*)d_in[20], (const float*)d_in[21],
        wpack);

    ctlf_k<<<dim3(256, 4, 4), blk, 0, stream>>>(hf, haarA, wpack + 8 * 10240, part);

    zero_k<<<dim3((8 * 32832 + TPB - 1) / TPB), blk, 0, stream>>>((unsigned int*)A2, (unsigned int*)B2);

    meanfin_k<<<dim3(2), blk, 0, stream>>>(part, amean, am0);
    tchain_k<<<dim3(4), dim3(64), 0, stream>>>(amean, t1_w, t1_b, t2_w, t2_b, t3_w, t3_b, theta);
    fcw_k<0><<<dim3(512), blk, 0, stream>>>(am0, fc1_w, fc1_b, am1, 64, 512);
    fcw_k<0><<<dim3(512), blk, 0, stream>>>(am1, fc2_w, fc2_b, am2, 512, 512);
    fcw_k<1><<<dim3(512), blk, 0, stream>>>(am2, fc3_w, fc3_b, am3, 512, 512);
    fcw_k<1><<<dim3(32), blk, 0, stream>>>(am3, g_w, g_b, gamma, 512, 32);
    fcw_k<2><<<dim3(32), blk, 0, stream>>>(am3, be_w, be_b, beta, 512, 32);
    packcdc_k<<<dim3(4), dim3(64), 0, stream>>>(cdc_w, theta, wpack);

    // --- heavy chain: enc1n + 8 pipelined dconv64p dispatches ---
    const dim3 gE(1024, 1, 4);
    const dim3 gP(256, 1, 4);
    float* outM = out + (size_t)4 * 3 * HW;

    enc1n_k<<<gE, blk, 0, stream>>>(x, wpack, A2);
    dconv64p_k<0><<<gP, blk, 0, stream>>>(A2, wpack + 1 * 10240, 0, B2, nullptr, nullptr, nullptr, nullptr, nullptr);
    dconv64p_k<0><<<gP, blk, 0, stream>>>(B2, wpack + 2 * 10240, 0, A2, nullptr, nullptr, nullptr, nullptr, nullptr);
    dconv64p_k<0><<<gP, blk, 0, stream>>>(A2, wpack + 3 * 10240, 0, B2, nullptr, nullptr, nullptr, nullptr, nullptr);
    dconv64p_k<0><<<gP, blk, 0, stream>>>(B2, wpack + 4 * 10240, 0, A2, nullptr, nullptr, nullptr, nullptr, nullptr);
    // cdc (theta folded per batch): A2 -> B2 = f_deco
    dconv64p_k<0><<<gP, blk, 0, stream>>>(A2, wpack + 12 * 10240, 10240, B2, nullptr, nullptr, nullptr, nullptr, nullptr);
    // res: B2 -> A2 (residual from LDS)
    dconv64p_k<2><<<gP, blk, 0, stream>>>(B2, wpack + 5 * 10240, 0, A2, gamma, beta, nullptr, nullptr, nullptr);
    // d1: A2 -> B2
    dconv64p_k<0><<<gP, blk, 0, stream>>>(A2, wpack + 6 * 10240, 0, B2, nullptr, nullptr, nullptr, nullptr, nullptr);
    // d2 + tanh + enhance -> outputs
    dconv64p_k<3><<<gP, blk, 0, stream>>>(B2, wpack + 7 * 10240, 0, nullptr, nullptr, nullptr, x, out, outM);
}

// Round 13
// 332.487 us; speedup vs baseline: 1.5003x; 1.0970x over previous
//
#include <hip/hip_runtime.h>
#include <hip/hip_bf16.h>
#include <cmath>

#define TPB 256

typedef __attribute__((ext_vector_type(8))) short s16x8;
typedef __attribute__((ext_vector_type(4))) float f32x4;
typedef unsigned short ushortT;

constexpr long long PSTR = 8454272;   // 514*514*32 ushorts per padded image
constexpr int HW = 512 * 512;

static __device__ __forceinline__ short f2bf(float f) {
    union { __hip_bfloat16 h; short s; } u;
    u.h = __float2bfloat16(f);
    return u.s;
}
static __device__ __forceinline__ float bf2f(unsigned short u) {
    union { unsigned int i; float f; } v;
    v.i = ((unsigned int)u) << 16;
    return v.f;
}
static __device__ __forceinline__ unsigned int pack2(float a, float b) {
    return (unsigned int)(unsigned short)f2bf(a) | ((unsigned int)(unsigned short)f2bf(b) << 16);
}

// global->LDS DMA, 16B per lane; lds dest = wave-uniform base + lane*16
#define GLOAD_LDS16(gp, lp) \
    __builtin_amdgcn_global_load_lds((const __attribute__((address_space(1))) void*)(gp), \
                                     (__attribute__((address_space(3))) void*)(lp), 16, 0, 0)

// ---------------------------------------------------------------------------
// Weight pack body. slot stride 10240 shorts; bias fp32 @ short-offset 9216.
// Packed ci position = ci_off + source ci. cdc fold: center tap -= theta*sum.
// ---------------------------------------------------------------------------
static __device__ void pack_body(const float* w, const float* bias, const float* theta,
                                 short* dst, int CO, int CI_src, int ci_off, int cog, int l)
{
    const int l15 = l & 15, sl = l >> 4;
    for (int t = 0; t < 9; ++t) {
        for (int mt = 0; mt < 2; ++mt) {
            const int co = cog * 32 + 16 * mt + l15;
            s16x8 p;
            #pragma unroll
            for (int i = 0; i < 8; ++i) {
                const int pci = 8 * sl + i;
                float val = 0.f;
                if (co < CO && pci >= ci_off && pci < ci_off + CI_src) {
                    const int ci = pci - ci_off;
                    val = w[((size_t)co * CI_src + ci) * 9 + t];
                    if (theta && t == 4) {
                        float s = 0.f;
                        for (int tt = 0; tt < 9; ++tt) s += w[((size_t)co * CI_src + ci) * 9 + tt];
                        val -= theta[0] * s;
                    }
                }
                p[i] = f2bf(val);
            }
            *(s16x8*)(dst + ((size_t)(t * 2 + mt) * 64 + l) * 8) = p;
        }
    }
    if (l < 32) {
        const int co = cog * 32 + l;
        ((float*)(dst + 9216))[l] = (bias && co < CO) ? bias[co] : 0.f;
    }
}

__global__ __launch_bounds__(64) void packall_k(
    const float* e1w, const float* e1b, const float* e2w, const float* e2b,
    const float* e3w, const float* e3b, const float* e4w, const float* e4b,
    const float* e5w, const float* e5b, const float* resw, const float* resb,
    const float* d1w, const float* d1b, const float* d2w, const float* d2b,
    const float* ctw, const float* ctb, const float* lfw, const float* lfb,
    short* wpack)
{
    const int s = blockIdx.x;
    const float *w, *b;
    int CO = 32, CI = 32, coff = 0, cog = 0;
    switch (s) {
        case 0: w = e1w; b = e1b; CI = 3; break;
        case 1: w = e2w; b = e2b; break;
        case 2: w = e3w; b = e3b; break;
        case 3: w = e4w; b = e4b; break;
        case 4: w = e5w; b = e5b; break;
        case 5: w = resw; b = resb; break;
        case 6: w = d1w; b = d1b; break;
        case 7: w = d2w; b = d2b; CO = 1; break;
        case 8: case 9: w = ctw; b = ctb; CO = 64; CI = 9; cog = s - 8; break;
        default: w = lfw; b = lfb; CO = 64; CI = 3; coff = 9; cog = s - 10; break;
    }
    pack_body(w, b, nullptr, wpack + (size_t)s * 10240, CO, CI, coff, cog, threadIdx.x);
}

__global__ __launch_bounds__(64) void packcdc_k(
    const float* cdcw, const float* theta, short* wpack)
{
    const int b = blockIdx.x;
    pack_body(cdcw, nullptr, theta + b, wpack + (size_t)(12 + b) * 10240, 32, 32, 0, 0, threadIdx.x);
}

// ---------------------------------------------------------------------------
// zero halo rings of 8 padded NHWC buffers (A2 z0..3, B2 z0..3)
// ---------------------------------------------------------------------------
__global__ __launch_bounds__(TPB) void zero_k(unsigned int* A2u, unsigned int* B2u)
{
    const int idx = blockIdx.x * TPB + threadIdx.x;
    if (idx >= 8 * 32832) return;
    const int q = idx / 32832, r = idx % 32832;
    unsigned int* P = (q < 4 ? A2u : B2u) + (size_t)(q & 3) * 4227136;
    const int RSU = 514 * 16;
    int off;
    if (r < 8224)       off = r;
    else if (r < 16448) off = 513 * RSU + (r - 8224);
    else if (r < 24640) { int u = r - 16448; off = (1 + (u >> 4)) * RSU + (u & 15); }
    else                { int u = r - 24640; off = (1 + (u >> 4)) * RSU + 513 * 16 + (u & 15); }
    P[off] = 0u;
}

// ---------------------------------------------------------------------------
// Fused DWT + ct + lf conv -> per-block channel partial sums.
// Computes the Haar DWT in-register from x (coalesced float2 quad loads),
// packs 12 channels (LH0-2,HL0-2,HH0-2,LL0-2) into swizzled bf16 LDS, then
// the standard narrow-tile MFMA loop with relu -> partial channel sums.
// blockIdx.y = cog: 0,1 = ct co 0-63 (slots 8,9), 2,3 = lf (slots 10,11).
// part[((z*4+cog)*256 + bid)*32 + c].
// ---------------------------------------------------------------------------
__global__ __launch_bounds__(TPB) void ctlf_k(
    const float* __restrict__ x0p, const short* __restrict__ wpack8,
    float* __restrict__ part)
{
    constexpr int RSX = 66;
    constexpr int ROWB = RSX * 64;
    __shared__ s16x8 lds_t[6 * RSX * 4];
    __shared__ float s_red[4][32];
    char* sb = (char*)lds_t;

    const int z = blockIdx.z, cog = blockIdx.y;
    const int bid = blockIdx.x;                 // 0..255
    const int x0 = (bid & 3) * 64, y0 = (bid >> 2) * 4;
    const int tid = threadIdx.x, lane = tid & 63, wv = tid >> 6;
    const int l15 = lane & 15, slot = lane >> 4;

    const short* wslot = wpack8 + (size_t)cog * 10240;
    const float* xz = x0p + (size_t)z * 3 * HW;

    s16x8 wf[9][2];
    #pragma unroll
    for (int t = 0; t < 9; ++t)
        #pragma unroll
        for (int mt = 0; mt < 2; ++mt)
            wf[t][mt] = *(const s16x8*)(wslot + ((size_t)(t * 2 + mt) * 64 + lane) * 8);

    // --- stage: 396 positions (6 rows x 66 lx); in-register Haar DWT ---
    #pragma unroll
    for (int j = 0; j < 2; ++j) {
        const int p = j * 256 + tid;
        if (p < 396) {
            const int row = p / 66, lx = p - row * 66;
            const int vs = (lx + (lx >> 2)) & 3;
            char* base = sb + (row * RSX + lx) * 64;
            const int sy = y0 + row - 1, sx = x0 + lx - 1;
            s16x8 pk0, pk1, zz;
            #pragma unroll
            for (int i = 0; i < 8; ++i) { pk0[i] = 0; pk1[i] = 0; zz[i] = 0; }
            if (sy >= 0 && sy < 256 && sx >= 0 && sx < 256) {
                #pragma unroll
                for (int c = 0; c < 3; ++c) {
                    const float* xp = xz + ((size_t)c * 512 + 2 * sy) * 512 + 2 * sx;
                    const float2 tp = *(const float2*)xp;
                    const float2 bt = *(const float2*)(xp + 512);
                    const float a = tp.x, b = tp.y, cc = bt.x, d = bt.y;
                    pk0[c]     = f2bf(0.5f * (a + b - cc - d));   // LH
                    pk0[3 + c] = f2bf(0.5f * (a - b + cc - d));   // HL
                    const float hh = 0.5f * (a - b - cc + d);
                    const float ll = 0.5f * (a + b + cc + d);
                    if (c < 2) pk0[6 + c] = f2bf(hh);
                    else       pk1[0]     = f2bf(hh);
                    pk1[1 + c] = f2bf(ll);                        // LL -> ci 9..11
                }
            }
            *(s16x8*)(base + ((0 ^ vs) << 4)) = pk0;
            *(s16x8*)(base + ((1 ^ vs) << 4)) = pk1;
            *(s16x8*)(base + ((2 ^ vs) << 4)) = zz;
            *(s16x8*)(base + ((3 ^ vs) << 4)) = zz;
        }
    }
    __syncthreads();

    const int xw = 16 * wv;
    int roff[3];
    #pragma unroll
    for (int dx = 0; dx < 3; ++dx) {
        const int lx = xw + dx + l15;
        const int vs = (lx + (lx >> 2)) & 3;
        roff[dx] = lx * 64 + ((slot ^ vs) << 4);
    }
    const float* bptr = (const float*)(wslot + 9216);

    float ps[2][4];
    #pragma unroll
    for (int mt = 0; mt < 2; ++mt)
        #pragma unroll
        for (int reg = 0; reg < 4; ++reg) ps[mt][reg] = 0.f;

    #pragma unroll
    for (int r2 = 0; r2 < 4; r2 += 2) {
        f32x4 acc[2][2];
        #pragma unroll
        for (int a = 0; a < 2; ++a)
            #pragma unroll
            for (int b = 0; b < 2; ++b)
                #pragma unroll
                for (int e = 0; e < 4; ++e) acc[a][b][e] = 0.f;

        #pragma unroll
        for (int dy = 0; dy < 3; ++dy) {
            const int rb0 = (r2 + dy) * ROWB;
            #pragma unroll
            for (int dx = 0; dx < 3; ++dx) {
                const int tap = dy * 3 + dx;
                const s16x8 b0 = *(const s16x8*)(sb + rb0 + roff[dx]);
                const s16x8 b1 = *(const s16x8*)(sb + rb0 + ROWB + roff[dx]);
                #pragma unroll
                for (int mt = 0; mt < 2; ++mt) {
                    acc[0][mt] = __builtin_amdgcn_mfma_f32_16x16x32_bf16(wf[tap][mt], b0, acc[0][mt], 0, 0, 0);
                    acc[1][mt] = __builtin_amdgcn_mfma_f32_16x16x32_bf16(wf[tap][mt], b1, acc[1][mt], 0, 0, 0);
                }
            }
        }

        #pragma unroll
        for (int rr = 0; rr < 2; ++rr)
            #pragma unroll
            for (int mt = 0; mt < 2; ++mt)
                #pragma unroll
                for (int reg = 0; reg < 4; ++reg)
                    ps[mt][reg] += fmaxf(acc[rr][mt][reg] + bptr[16 * mt + 4 * slot + reg], 0.f);
    }

    #pragma unroll
    for (int mt = 0; mt < 2; ++mt)
        #pragma unroll
        for (int reg = 0; reg < 4; ++reg) {
            #pragma unroll
            for (int o = 1; o < 16; o <<= 1)
                ps[mt][reg] += __shfl_xor(ps[mt][reg], o, 64);
        }
    #pragma unroll
    for (int mt = 0; mt < 2; ++mt)
        #pragma unroll
        for (int reg = 0; reg < 4; ++reg)
            if (l15 == mt * 4 + reg)
                s_red[wv][16 * mt + 4 * slot + reg] = ps[mt][reg];
    __syncthreads();
    if (tid < 32) {
        const float s = s_red[0][tid] + s_red[1][tid] + s_red[2][tid] + s_red[3][tid];
        part[(((size_t)z * 4 + cog) * 256 + bid) * 32 + tid] = s;
    }
}

// ---------------------------------------------------------------------------
// enc1: narrow 64px x 4row conv, fp32 NCHW 3-ch input -> padded NHWC bf16.
// Position-based staging (all lanes active, coalesced per-channel loads).
// ---------------------------------------------------------------------------
__global__ __launch_bounds__(TPB) void enc1n_k(
    const float* __restrict__ x0p, const short* __restrict__ wslot,
    ushortT* __restrict__ outP0)
{
    constexpr int RSX = 66;
    constexpr int ROWB = RSX * 64;
    __shared__ s16x8 lds_t[6 * RSX * 4];
    char* sb = (char*)lds_t;

    const int z = blockIdx.z;
    const float* xin = x0p + (size_t)z * 3 * HW;

    const int tid = threadIdx.x, lane = tid & 63, wv = tid >> 6;
    const int bid = blockIdx.x;
    const int swz = (bid & 7) * 128 + (bid >> 3);
    const int x0 = (swz & 7) * 64, y0 = (swz >> 3) * 4;
    const int l15 = lane & 15, slot = lane >> 4;

    s16x8 wf[9][2];
    #pragma unroll
    for (int t = 0; t < 9; ++t)
        #pragma unroll
        for (int mt = 0; mt < 2; ++mt)
            wf[t][mt] = *(const s16x8*)(wslot + ((size_t)(t * 2 + mt) * 64 + lane) * 8);

    #pragma unroll
    for (int j = 0; j < 2; ++j) {
        const int p = j * 256 + tid;
        if (p < 396) {
            const int row = p / 66, lx = p - row * 66;
            const int vs = (lx + (lx >> 2)) & 3;
            char* base = sb + (row * RSX + lx) * 64;
            const int gy = y0 + row - 1, gx = x0 + lx - 1;
            s16x8 pk, zz;
            #pragma unroll
            for (int i = 0; i < 8; ++i) { pk[i] = 0; zz[i] = 0; }
            if (gy >= 0 && gy < 512 && gx >= 0 && gx < 512) {
                #pragma unroll
                for (int c = 0; c < 3; ++c)
                    pk[c] = f2bf(xin[((size_t)c * 512 + gy) * 512 + gx]);
            }
            *(s16x8*)(base + ((0 ^ vs) << 4)) = pk;
            *(s16x8*)(base + ((1 ^ vs) << 4)) = zz;
            *(s16x8*)(base + ((2 ^ vs) << 4)) = zz;
            *(s16x8*)(base + ((3 ^ vs) << 4)) = zz;
        }
    }
    __syncthreads();

    const int xw = 16 * wv;
    int roff[3];
    #pragma unroll
    for (int dx = 0; dx < 3; ++dx) {
        const int lx = xw + dx + l15;
        const int vs = (lx + (lx >> 2)) & 3;
        roff[dx] = lx * 64 + ((slot ^ vs) << 4);
    }
    const float* bptr = (const float*)(wslot + 9216);
    ushortT* outP = outP0 + (size_t)z * PSTR;

    #pragma unroll
    for (int r2 = 0; r2 < 4; r2 += 2) {
        f32x4 acc[2][2];
        #pragma unroll
        for (int a = 0; a < 2; ++a)
            #pragma unroll
            for (int b = 0; b < 2; ++b)
                #pragma unroll
                for (int e = 0; e < 4; ++e) acc[a][b][e] = 0.f;

        #pragma unroll
        for (int dy = 0; dy < 3; ++dy) {
            const int rb0 = (r2 + dy) * ROWB;
            #pragma unroll
            for (int dx = 0; dx < 3; ++dx) {
                const int tap = dy * 3 + dx;
                const s16x8 b0 = *(const s16x8*)(sb + rb0 + roff[dx]);
                const s16x8 b1 = *(const s16x8*)(sb + rb0 + ROWB + roff[dx]);
                #pragma unroll
                for (int mt = 0; mt < 2; ++mt) {
                    acc[0][mt] = __builtin_amdgcn_mfma_f32_16x16x32_bf16(wf[tap][mt], b0, acc[0][mt], 0, 0, 0);
                    acc[1][mt] = __builtin_amdgcn_mfma_f32_16x16x32_bf16(wf[tap][mt], b1, acc[1][mt], 0, 0, 0);
                }
            }
        }

        #pragma unroll
        for (int rr = 0; rr < 2; ++rr) {
            const int gy = y0 + r2 + rr;
            const int gx = x0 + xw + l15;
            #pragma unroll
            for (int mt = 0; mt < 2; ++mt) {
                const size_t off = ((size_t)(gy + 1) * 514 + gx + 1) * 32 + 16 * mt + 4 * slot;
                float v[4];
                #pragma unroll
                for (int reg = 0; reg < 4; ++reg)
                    v[reg] = fmaxf(acc[rr][mt][reg] + bptr[16 * mt + 4 * slot + reg], 0.f);
                *(uint2*)(outP + off) = make_uint2(pack2(v[0], v[1]), pack2(v[2], v[3]));
            }
        }
    }
}

// ---------------------------------------------------------------------------
// Pipelined double-buffered DMA conv on padded NHWC bf16 (unchanged r12).
// ---------------------------------------------------------------------------
template<int EPI>
__global__ __launch_bounds__(TPB) void dconv64p_k(
    const ushortT* __restrict__ inP0, const short* __restrict__ wbase, int wstr,
    ushortT* __restrict__ outP0,
    const float* __restrict__ gamma0, const float* __restrict__ beta0,
    const float* __restrict__ xorig0, float* __restrict__ outE0, float* __restrict__ outM0)
{
    constexpr int MT = (EPI == 3) ? 1 : 2;
    constexpr int RSX = 66;
    constexpr int ROWB = RSX * 64;
    constexpr int BUFB = 6 * RSX * 64;
    __shared__ s16x8 lds_t[2 * 6 * RSX * 4];
    char* sbase = (char*)lds_t;

    const int z = blockIdx.z;
    const ushortT* inP = inP0 + (size_t)z * PSTR;
    const short* wslot = wbase + (size_t)z * wstr;

    const int tid = threadIdx.x, lane = tid & 63, wv = tid >> 6;
    const int bid = blockIdx.x;
    const int xcd = bid & 7, idx = bid >> 3;
    const int x0 = (idx & 7) * 64;
    const int yband = xcd * 4 + (idx >> 3);
    const int l15 = lane & 15, slot = lane >> 4;

    s16x8 wf[9][MT];
    #pragma unroll
    for (int t = 0; t < 9; ++t)
        #pragma unroll
        for (int mt = 0; mt < MT; ++mt)
            wf[t][mt] = *(const s16x8*)(wslot + ((size_t)(t * 2 + mt) * 64 + lane) * 8);

    const int xw = 16 * wv;
    int roff[3];
    #pragma unroll
    for (int dx = 0; dx < 3; ++dx) {
        const int lx = xw + dx + l15;
        const int vs = (lx + (lx >> 2)) & 3;
        roff[dx] = lx * 64 + ((slot ^ vs) << 4);
    }
    const float* bptr = (const float*)(wslot + 9216);

    auto stage = [&](int t, int b) {
        const int y0 = yband * 16 + 4 * t;
        char* sb = sbase + b * BUFB;
        #pragma unroll
        for (int j = 0; j < 6; ++j) {
            const int p = j * 256 + tid;
            const int row = p / 264;
            const int rem = p - row * 264;
            const int lx = rem >> 2, osl = rem & 3;
            const int o = osl ^ ((lx + (lx >> 2)) & 3);
            const ushortT* gp = inP + ((size_t)(y0 + row) * 514 + x0 + lx) * 32 + o * 8;
            GLOAD_LDS16(gp, sb + (size_t)(j * 256 + wv * 64) * 16);
        }
        if (tid < 48) {
            const int p = 1536 + tid;
            const int row = p / 264;
            const int rem = p - row * 264;
            const int lx = rem >> 2, osl = rem & 3;
            const int o = osl ^ ((lx + (lx >> 2)) & 3);
            const ushortT* gp = inP + ((size_t)(y0 + row) * 514 + x0 + lx) * 32 + o * 8;
            GLOAD_LDS16(gp, sb + (size_t)1536 * 16);
        }
    };

    stage(0, 0);

    #pragma unroll 1
    for (int t = 0; t < 4; ++t) {
        __syncthreads();
        if (t < 3) stage(t + 1, (t + 1) & 1);
        char* sb = sbase + (t & 1) * BUFB;
        const int y0t = yband * 16 + 4 * t;

        #pragma unroll
        for (int r2 = 0; r2 < 4; r2 += 2) {
            f32x4 acc[2][MT];
            #pragma unroll
            for (int a = 0; a < 2; ++a)
                #pragma unroll
                for (int b = 0; b < MT; ++b)
                    #pragma unroll
                    for (int e = 0; e < 4; ++e) acc[a][b][e] = 0.f;

            #pragma unroll
            for (int dy = 0; dy < 3; ++dy) {
                const int rb0 = (r2 + dy) * ROWB;
                #pragma unroll
                for (int dx = 0; dx < 3; ++dx) {
                    const int tap = dy * 3 + dx;
                    const s16x8 b0 = *(const s16x8*)(sb + rb0 + roff[dx]);
                    const s16x8 b1 = *(const s16x8*)(sb + rb0 + ROWB + roff[dx]);
                    #pragma unroll
                    for (int mt = 0; mt < MT; ++mt) {
                        acc[0][mt] = __builtin_amdgcn_mfma_f32_16x16x32_bf16(wf[tap][mt], b0, acc[0][mt], 0, 0, 0);
                        acc[1][mt] = __builtin_amdgcn_mfma_f32_16x16x32_bf16(wf[tap][mt], b1, acc[1][mt], 0, 0, 0);
                    }
                }
            }

            #pragma unroll
            for (int rr = 0; rr < 2; ++rr) {
                const int gy = y0t + r2 + rr;
                const int gx = x0 + xw + l15;
                if constexpr (EPI == 3) {
                    if (slot == 0) {
                        const float* xorig = xorig0 + (size_t)z * 3 * HW;
                        float* outE = outE0 + (size_t)z * 3 * HW;
                        float* outM = outM0 + (size_t)z * HW;
                        const float om = tanhf(acc[rr][0][0] + bptr[0]);
                        outM[(size_t)gy * 512 + gx] = om;
                        #pragma unroll
                        for (int c = 0; c < 3; ++c) {
                            const size_t xi = ((size_t)c * 512 + gy) * 512 + gx;
                            const float xv = xorig[xi];
                            outE[xi] = xv + om * (xv * xv - xv);
                        }
                    }
                } else {
                    ushortT* outP = outP0 + (size_t)z * PSTR;
                    #pragma unroll
                    for (int mt = 0; mt < MT; ++mt) {
                        const size_t off = ((size_t)(gy + 1) * 514 + gx + 1) * 32 + 16 * mt + 4 * slot;
                        float v[4];
                        #pragma unroll
                        for (int reg = 0; reg < 4; ++reg)
                            v[reg] = acc[rr][mt][reg] + bptr[16 * mt + 4 * slot + reg];
                        if constexpr (EPI == 0) {
                            #pragma unroll
                            for (int reg = 0; reg < 4; ++reg) v[reg] = fmaxf(v[reg], 0.f);
                        } else if constexpr (EPI == 2) {
                            const int prow = r2 + rr + 1;
                            const int lxr = xw + l15 + 1;
                            const int vsr = (lxr + (lxr >> 2)) & 3;
                            const int oo = (2 * mt + (slot >> 1)) ^ vsr;
                            const uint2 din = *(const uint2*)(sb + (prow * RSX + lxr) * 64 + (oo << 4) + ((slot & 1) << 3));
                            const float* gamma = gamma0 + 32 * z;
                            const float* beta  = beta0 + 32 * z;
                            const int cb = 16 * mt + 4 * slot;
                            v[0] = bf2f((unsigned short)(din.x & 0xffff)) + gamma[cb + 0] * v[0] + beta[cb + 0];
                            v[1] = bf2f((unsigned short)(din.x >> 16))    + gamma[cb + 1] * v[1] + beta[cb + 1];
                            v[2] = bf2f((unsigned short)(din.y & 0xffff)) + gamma[cb + 2] * v[2] + beta[cb + 2];
                            v[3] = bf2f((unsigned short)(din.y >> 16))    + gamma[cb + 3] * v[3] + beta[cb + 3];
                        }
                        *(uint2*)(outP + off) = make_uint2(pack2(v[0], v[1]), pack2(v[2], v[3]));
                    }
                }
            }
        }
    }
}

// ---------------------------------------------------------------------------
// Finish channel means from ctlf partials.
// ---------------------------------------------------------------------------
__global__ __launch_bounds__(TPB) void meanfin_k(
    const float* __restrict__ part, float* __restrict__ amean, float* __restrict__ am0)
{
    const int br = blockIdx.x;
    const int o = threadIdx.x;
    const int z = o >> 6, co = o & 63;
    const int cog = (br ? 2 : 0) + (co >> 5), c = co & 31;
    const float* p = part + (((size_t)z * 4 + cog) * 256) * 32 + c;
    float s = 0.f;
    for (int j = 0; j < 256; ++j) s += p[j * 32];
    (br ? am0 : amean)[z * 64 + co] = s * (1.f / 65536.f);
}

// ---------------------------------------------------------------------------
// t1->t2->t3 chain, blockIdx.x = b
// ---------------------------------------------------------------------------
__global__ __launch_bounds__(64) void tchain_k(
    const float* __restrict__ amean,
    const float* __restrict__ t1w, const float* __restrict__ t1b,
    const float* __restrict__ t2w, const float* __restrict__ t2b,
    const float* __restrict__ t3w, const float* __restrict__ t3b,
    float* __restrict__ theta)
{
    const int b = blockIdx.x;
    const float* am = amean + b * 64;
    __shared__ float a0[64], a1[64], a2[64];
    const int co = threadIdx.x;
    a0[co] = am[co];
    __syncthreads();
    float s = t1b[co];
    #pragma unroll 8
    for (int ci = 0; ci < 64; ++ci) s = fmaf(t1w[co * 64 + ci], a0[ci], s);
    a1[co] = fmaxf(s, 0.f);
    __syncthreads();
    s = t2b[co];
    #pragma unroll 8
    for (int ci = 0; ci < 64; ++ci) s = fmaf(t2w[co * 64 + ci], a1[ci], s);
    a2[co] = fmaxf(s, 0.f);
    __syncthreads();
    if (co == 0) {
        float v = t3b[0];
        for (int ci = 0; ci < 64; ++ci) v = fmaf(t3w[ci], a2[ci], v);
        theta[b] = 1.f / (1.f + expf(-v));
    }
}

// ---------------------------------------------------------------------------
// wave-per-output FC. ACT 0 relu, 1 sigmoid, 2 tanh.
// ---------------------------------------------------------------------------
template<int ACT>
__global__ __launch_bounds__(TPB) void fcw_k(
    const float* __restrict__ in, const float* __restrict__ w,
    const float* __restrict__ bias, float* __restrict__ out, int K, int N)
{
    const int lane = threadIdx.x & 63, wv = threadIdx.x >> 6;
    const int idx = blockIdx.x * 4 + wv;
    if (idx >= 4 * N) return;
    const int b = idx / N, co = idx % N;
    float s = 0.f;
    for (int k = lane * 4; k < K; k += 256) {
        const float4 wv4 = *(const float4*)(w + (size_t)co * K + k);
        const float4 iv  = *(const float4*)(in + (size_t)b * K + k);
        s += wv4.x * iv.x + wv4.y * iv.y + wv4.z * iv.z + wv4.w * iv.w;
    }
    #pragma unroll
    for (int o = 32; o > 0; o >>= 1) s += __shfl_xor(s, o, 64);
    if (lane == 0) {
        s += bias[co];
        if (ACT == 0) s = fmaxf(s, 0.f);
        else if (ACT == 1) s = 1.f / (1.f + expf(-s));
        else s = tanhf(s);
        out[(size_t)b * N + co] = s;
    }
}

// ---------------------------------------------------------------------------
extern "C" void kernel_launch(void* const* d_in, const int* in_sizes, int n_in,
                              void* d_out, int out_size, void* d_ws, size_t ws_size,
                              hipStream_t stream)
{
    const float* x      = (const float*)d_in[0];
    const float* cdc_w  = (const float*)d_in[11];
    const float* t1_w   = (const float*)d_in[14];
    const float* t1_b   = (const float*)d_in[15];
    const float* t2_w   = (const float*)d_in[16];
    const float* t2_b   = (const float*)d_in[17];
    const float* t3_w   = (const float*)d_in[18];
    const float* t3_b   = (const float*)d_in[19];
    const float* fc1_w  = (const float*)d_in[22];
    const float* fc1_b  = (const float*)d_in[23];
    const float* fc2_w  = (const float*)d_in[24];
    const float* fc2_b  = (const float*)d_in[25];
    const float* fc3_w  = (const float*)d_in[26];
    const float* fc3_b  = (const float*)d_in[27];
    const float* g_w    = (const float*)d_in[28];
    const float* g_b    = (const float*)d_in[29];
    const float* be_w   = (const float*)d_in[30];
    const float* be_b   = (const float*)d_in[31];

    float* out = (float*)d_out;

    // workspace layout (no more haarA/hf -- DWT fused into ctlf)
    ushortT* A2 = (ushortT*)d_ws;                  // 4 x 16.9 MB
    ushortT* B2 = A2 + 4 * PSTR;                   // 4 x 16.9 MB
    float* part  = (float*)(B2 + 4 * PSTR);        // 131072
    float* amean = part + 131072;                  // 256
    float* am0   = amean + 256;                    // 256
    float* am1   = am0 + 256;                      // 2048
    float* am2   = am1 + 2048;
    float* am3   = am2 + 2048;
    float* theta = am3 + 2048;                     // 4
    float* gamma = theta + 4;                      // 128 [4][32]
    float* beta  = gamma + 128;                    // 128
    short* wpack = (short*)(beta + 128);           // 16 x 10240 shorts
    const size_t need_bytes = (size_t)((char*)(wpack + 16 * 10240) - (char*)d_ws);
    if (ws_size < need_bytes) return;

    const dim3 blk(TPB);

    // --- phase A ---
    packall_k<<<dim3(12), dim3(64), 0, stream>>>(
        (const float*)d_in[1], (const float*)d_in[2], (const float*)d_in[3], (const float*)d_in[4],
        (const float*)d_in[5], (const float*)d_in[6], (const float*)d_in[7], (const float*)d_in[8],
        (const float*)d_in[9], (const float*)d_in[10], (const float*)d_in[32], (const float*)d_in[33],
        (const float*)d_in[34], (const float*)d_in[35], (const float*)d_in[36], (const float*)d_in[37],
        (const float*)d_in[12], (const float*)d_in[13], (const float*)d_in[20], (const float*)d_in[21],
        wpack);

    zero_k<<<dim3((8 * 32832 + TPB - 1) / TPB), blk, 0, stream>>>((unsigned int*)A2, (unsigned int*)B2);

    // fused DWT + ct + lf conv -> channel partials (one dispatch, reads x)
    ctlf_k<<<dim3(256, 4, 4), blk, 0, stream>>>(x, wpack + 8 * 10240, part);

    meanfin_k<<<dim3(2), blk, 0, stream>>>(part, amean, am0);
    tchain_k<<<dim3(4), dim3(64), 0, stream>>>(amean, t1_w, t1_b, t2_w, t2_b, t3_w, t3_b, theta);
    fcw_k<0><<<dim3(512), blk, 0, stream>>>(am0, fc1_w, fc1_b, am1, 64, 512);
    fcw_k<0><<<dim3(512), blk, 0, stream>>>(am1, fc2_w, fc2_b, am2, 512, 512);
    fcw_k<1><<<dim3(512), blk, 0, stream>>>(am2, fc3_w, fc3_b, am3, 512, 512);
    fcw_k<1><<<dim3(32), blk, 0, stream>>>(am3, g_w, g_b, gamma, 512, 32);
    fcw_k<2><<<dim3(32), blk, 0, stream>>>(am3, be_w, be_b, beta, 512, 32);
    packcdc_k<<<dim3(4), dim3(64), 0, stream>>>(cdc_w, theta, wpack);

    // --- heavy chain: enc1n + 8 pipelined dconv64p dispatches ---
    const dim3 gE(1024, 1, 4);
    const dim3 gP(256, 1, 4);
    float* outM = out + (size_t)4 * 3 * HW;

    enc1n_k<<<gE, blk, 0, stream>>>(x, wpack, A2);
    dconv64p_k<0><<<gP, blk, 0, stream>>>(A2, wpack + 1 * 10240, 0, B2, nullptr, nullptr, nullptr, nullptr, nullptr);
    dconv64p_k<0><<<gP, blk, 0, stream>>>(B2, wpack + 2 * 10240, 0, A2, nullptr, nullptr, nullptr, nullptr, nullptr);
    dconv64p_k<0><<<gP, blk, 0, stream>>>(A2, wpack + 3 * 10240, 0, B2, nullptr, nullptr, nullptr, nullptr, nullptr);
    dconv64p_k<0><<<gP, blk, 0, stream>>>(B2, wpack + 4 * 10240, 0, A2, nullptr, nullptr, nullptr, nullptr, nullptr);
    // cdc (theta folded per batch): A2 -> B2 = f_deco
    dconv64p_k<0><<<gP, blk, 0, stream>>>(A2, wpack + 12 * 10240, 10240, B2, nullptr, nullptr, nullptr, nullptr, nullptr);
    // res: B2 -> A2 (residual from LDS)
    dconv64p_k<2><<<gP, blk, 0, stream>>>(B2, wpack + 5 * 10240, 0, A2, gamma, beta, nullptr, nullptr, nullptr);
    // d1: A2 -> B2
    dconv64p_k<0><<<gP, blk, 0, stream>>>(A2, wpack + 6 * 10240, 0, B2, nullptr, nullptr, nullptr, nullptr, nullptr);
    // d2 + tanh + enhance -> outputs
    dconv64p_k<3><<<gP, blk, 0, stream>>>(B2, wpack + 7 * 10240, 0, nullptr, nullptr, nullptr, x, out, outM);
}